// Round 5
// baseline (562.935 us; speedup 1.0000x reference)
//
#include <hip/hip_runtime.h>

// ---------------------------------------------------------------------------
// GAT (heads=1) x2 layers x2 branches + FC head, fp32.
// R5: fix R4's non-bijective W-tile swizzle (cols 60-63 collided with 64-67).
// New swizzle: float4-group index g -> g ^ ((g>>3)&1) — an involution, spreads
// each b128 read 2-way across bank sets (free). Keeps: transposed A-tile
// (b128 frags), K-tile global->reg->LDS pipeline, fused attn epilogue,
// 16-deep aggregation gather. Softmax without max pass (shift-invariant;
// self-loops guarantee nonempty segments; |logits| small).
// ---------------------------------------------------------------------------

// bijective LDS swizzle on float4-group index (0..31): xor bit0 with bit3
__device__ __forceinline__ int wswz(int g) { return g ^ ((g >> 3) & 1); }

// C[M,128] = (relu_in? relu(A) : A)[M,K] @ W[K,128] (+ bias)
// If a_s != nullptr: also es[row] = C_row · a_s, ed[row] = C_row · a_d.
__global__ __launch_bounds__(256) void gemm_k(
    const float* __restrict__ A, const float* __restrict__ W,
    const float* __restrict__ bias,
    const float* __restrict__ a_s, const float* __restrict__ a_d,
    float* __restrict__ C, float* __restrict__ es, float* __restrict__ ed,
    int M, int K, int relu_in)
{
  __shared__ float Ast[32][68];     // [kk][row], pad 68: b128 frag reads conflict-free
  __shared__ float Ws[32][128];     // [kk][swizzled float4 groups]
  const int tid = threadIdx.x;
  const int bm  = blockIdx.x * 64;
  const int tc  = tid & 15;
  const int tr  = tid >> 4;

  float acc[4][8];
#pragma unroll
  for (int r = 0; r < 4; ++r)
#pragma unroll
    for (int c = 0; c < 8; ++c) acc[r][c] = 0.f;

  const int T = K >> 5;
  float4 areg[2], wreg[4];

  auto load_regs = [&](int k0) {
#pragma unroll
    for (int t = 0; t < 2; ++t) {
      int v   = tid + t * 256;
      int row = v >> 3;
      int kq  = (v & 7) * 4;
      float4 av = make_float4(0.f, 0.f, 0.f, 0.f);
      if (bm + row < M)
        av = *reinterpret_cast<const float4*>(A + (size_t)(bm + row) * K + k0 + kq);
      if (relu_in) {
        av.x = fmaxf(av.x, 0.f); av.y = fmaxf(av.y, 0.f);
        av.z = fmaxf(av.z, 0.f); av.w = fmaxf(av.w, 0.f);
      }
      areg[t] = av;
    }
#pragma unroll
    for (int t = 0; t < 4; ++t) {
      int v  = tid + t * 256;
      int kr = v >> 5;
      int nq = (v & 31) * 4;
      wreg[t] = *reinterpret_cast<const float4*>(W + (size_t)(k0 + kr) * 128 + nq);
    }
  };
  auto write_lds = [&]() {
#pragma unroll
    for (int t = 0; t < 2; ++t) {
      int v   = tid + t * 256;
      int row = v >> 3;
      int kq  = (v & 7) * 4;
      Ast[kq + 0][row] = areg[t].x;
      Ast[kq + 1][row] = areg[t].y;
      Ast[kq + 2][row] = areg[t].z;
      Ast[kq + 3][row] = areg[t].w;
    }
#pragma unroll
    for (int t = 0; t < 4; ++t) {
      int v  = tid + t * 256;
      int kr = v >> 5;
      int g  = v & 31;                       // float4 group index
      *reinterpret_cast<float4*>(&Ws[kr][wswz(g) * 4]) = wreg[t];
    }
  };

  // ---- pipelined K loop (single LDS buffer, 2 barriers/tile) ----
  load_regs(0);
  write_lds();
  __syncthreads();
  for (int t = 0;; ++t) {
    if (t + 1 < T) load_regs((t + 1) * 32);   // global loads in flight across compute

#pragma unroll 8
    for (int kk = 0; kk < 32; ++kk) {
      float4 a4 = *reinterpret_cast<const float4*>(&Ast[kk][tr * 4]);
      float4 w0 = *reinterpret_cast<const float4*>(&Ws[kk][wswz(tc * 2) * 4]);
      float4 w1 = *reinterpret_cast<const float4*>(&Ws[kk][wswz(tc * 2 + 1) * 4]);
      float a[4] = {a4.x, a4.y, a4.z, a4.w};
      float w[8] = {w0.x, w0.y, w0.z, w0.w, w1.x, w1.y, w1.z, w1.w};
#pragma unroll
      for (int r = 0; r < 4; ++r)
#pragma unroll
        for (int c = 0; c < 8; ++c) acc[r][c] += a[r] * w[c];
    }

    if (t + 1 >= T) break;
    __syncthreads();     // everyone done reading LDS
    write_lds();         // waits on the in-flight global loads
    __syncthreads();
  }

  // ---- C write ----
#pragma unroll
  for (int r = 0; r < 4; ++r) {
    int row = bm + tr * 4 + r;
    if (row >= M) continue;
    float b[8] = {0.f,0.f,0.f,0.f,0.f,0.f,0.f,0.f};
    if (bias) {
#pragma unroll
      for (int c = 0; c < 8; ++c) b[c] = bias[tc * 8 + c];
    }
    float4 o0 = make_float4(acc[r][0] + b[0], acc[r][1] + b[1], acc[r][2] + b[2], acc[r][3] + b[3]);
    float4 o1 = make_float4(acc[r][4] + b[4], acc[r][5] + b[5], acc[r][6] + b[6], acc[r][7] + b[7]);
    *reinterpret_cast<float4*>(C + (size_t)row * 128 + tc * 8)     = o0;
    *reinterpret_cast<float4*>(C + (size_t)row * 128 + tc * 8 + 4) = o1;
  }

  // ---- fused attn epilogue: es/ed per row ----
  if (a_s) {
    float asv[8], adv[8];
#pragma unroll
    for (int c = 0; c < 8; ++c) { asv[c] = a_s[tc * 8 + c]; adv[c] = a_d[tc * 8 + c]; }
#pragma unroll
    for (int r = 0; r < 4; ++r) {
      float ps = 0.f, pd = 0.f;
#pragma unroll
      for (int c = 0; c < 8; ++c) { ps += acc[r][c] * asv[c]; pd += acc[r][c] * adv[c]; }
#pragma unroll
      for (int o = 1; o < 16; o <<= 1) {
        ps += __shfl_xor(ps, o, 64);
        pd += __shfl_xor(pd, o, 64);
      }
      int row = bm + tr * 4 + r;
      if (tc == 0 && row < M) { es[row] = ps; ed[row] = pd; }
    }
  }
}

// ---------------- CSR build (by dst, self-loop at slot off[i]) ----------------

__global__ __launch_bounds__(256) void deg_init_k(int* __restrict__ deg, int* __restrict__ off, int N, int total)
{
  int i = blockIdx.x * 256 + threadIdx.x;
  if (i < N) deg[i] = 1;                 // self loop
  if (i == 0) off[N] = total;
}

__global__ __launch_bounds__(256) void deg_k(const int* __restrict__ dst, int* __restrict__ deg, int E)
{
  int e = blockIdx.x * 256 + threadIdx.x;
  if (e < E) atomicAdd(&deg[dst[e]], 1);
}

// exclusive scan, 1024 elements per block (4/thread)
__global__ __launch_bounds__(256) void scan1_k(
    const int* __restrict__ deg, int* __restrict__ off, int* __restrict__ bsum, int N)
{
  __shared__ int ts[256];
  int base = blockIdx.x * 1024 + threadIdx.x * 4;
  int v[4]; int s = 0;
#pragma unroll
  for (int t = 0; t < 4; ++t) { v[t] = (base + t < N) ? deg[base + t] : 0; s += v[t]; }
  ts[threadIdx.x] = s;
  __syncthreads();
  int mine = s;
#pragma unroll
  for (int o = 1; o < 256; o <<= 1) {
    int x = (threadIdx.x >= o) ? ts[threadIdx.x - o] : 0;
    __syncthreads();
    ts[threadIdx.x] += x;
    __syncthreads();
  }
  int run = ts[threadIdx.x] - mine;
#pragma unroll
  for (int t = 0; t < 4; ++t) {
    if (base + t < N) off[base + t] = run;
    run += v[t];
  }
  if (threadIdx.x == 255) bsum[blockIdx.x] = ts[255];
}

__global__ __launch_bounds__(256) void scan2_k(int* __restrict__ bsum, int nb)
{
  __shared__ int ts[256];
  int v = (threadIdx.x < nb) ? bsum[threadIdx.x] : 0;
  ts[threadIdx.x] = v;
  __syncthreads();
  int mine = v;
#pragma unroll
  for (int o = 1; o < 256; o <<= 1) {
    int x = (threadIdx.x >= o) ? ts[threadIdx.x - o] : 0;
    __syncthreads();
    ts[threadIdx.x] += x;
    __syncthreads();
  }
  if (threadIdx.x < nb) bsum[threadIdx.x] = ts[threadIdx.x] - mine;
}

__global__ __launch_bounds__(256) void scan3_k(int* __restrict__ off, const int* __restrict__ bsum, int N)
{
  int i = blockIdx.x * 256 + threadIdx.x;
  if (i < N) off[i] += bsum[i >> 10];
}

__global__ __launch_bounds__(256) void fill_self_k(
    const int* __restrict__ off, int* __restrict__ srcs, int* __restrict__ cur, int N)
{
  int i = blockIdx.x * 256 + threadIdx.x;
  if (i < N) { srcs[off[i]] = i; cur[i] = 1; }
}

__global__ __launch_bounds__(256) void fill_edge_k(
    const int* __restrict__ src, const int* __restrict__ dst,
    const int* __restrict__ off, int* __restrict__ cur, int* __restrict__ srcs, int E)
{
  int e = blockIdx.x * 256 + threadIdx.x;
  if (e < E) {
    int d = dst[e];
    int j = off[d] + atomicAdd(&cur[d], 1);
    srcs[j] = src[e];
  }
}

// ---------------- fused per-node softmax + aggregate (one wave per node) -----
__global__ __launch_bounds__(256) void gat_aggr_k(
    const int* __restrict__ off, const int* __restrict__ srcs,
    const float* __restrict__ es, const float* __restrict__ ed,
    const float* __restrict__ h, const float* __restrict__ bias,
    float* __restrict__ out, int N)
{
  int w    = (blockIdx.x * 256 + threadIdx.x) >> 6;
  int lane = threadIdx.x & 63;
  if (w >= N) return;
  int b  = off[w];
  int e2 = off[w + 1];
  float edv = ed[w];
  float ax = 0.f, ay = 0.f, dsum = 0.f;

  for (int c0 = b; c0 < e2; c0 += 64) {
    int nc = e2 - c0; if (nc > 64) nc = 64;
    int  sl = srcs[c0 + (lane < nc ? lane : 0)];
    float pl = 0.f;
    if (lane < nc) {
      float l = es[sl] + edv;
      l = (l > 0.f) ? l : 0.2f * l;
      pl = expf(l);
    }
    dsum += pl;

    for (int e = 0; e < nc; e += 16) {
      float2 hv[16]; float pp[16];
#pragma unroll
      for (int k = 0; k < 16; ++k) {
        int  ok  = (e + k) < nc;
        int  idx = ok ? (e + k) : 0;
        int  s   = __shfl(sl, idx, 64);
        pp[k]    = ok ? __shfl(pl, idx, 64) : 0.f;
        hv[k]    = *reinterpret_cast<const float2*>(h + (size_t)s * 128 + lane * 2);
      }
#pragma unroll
      for (int k = 0; k < 16; ++k) { ax += pp[k] * hv[k].x; ay += pp[k] * hv[k].y; }
    }
  }

#pragma unroll
  for (int o = 32; o > 0; o >>= 1) dsum += __shfl_xor(dsum, o, 64);
  float inv = 1.f / dsum;
  float2 o2 = make_float2(ax * inv + bias[lane * 2], ay * inv + bias[lane * 2 + 1]);
  *reinterpret_cast<float2*>(out + (size_t)w * 128 + lane * 2) = o2;
}

// fcbuf[i, 0:128] = relu(hx[idx[i]]), [128:256] = relu(hy[idx[i]])
__global__ __launch_bounds__(256) void gather_k(
    const int* __restrict__ idx, const float* __restrict__ hx,
    const float* __restrict__ hy, float* __restrict__ outb, int M)
{
  int t = blockIdx.x * 256 + threadIdx.x;
  if (t >= M * 256) return;
  int i = t >> 8, c = t & 255;
  int r = idx[i];
  float v = (c < 128) ? hx[(size_t)r * 128 + c] : hy[(size_t)r * 128 + (c - 128)];
  outb[t] = fmaxf(v, 0.f);
}

// out[i, 0:64] = relu(fc[i,:]) @ Wout[128,64] + bout   (one wave per row)
__global__ __launch_bounds__(256) void head_k(
    const float* __restrict__ fc, const float* __restrict__ Wout,
    const float* __restrict__ bout, float* __restrict__ out, int M)
{
  __shared__ float rowbuf[4][128];
  int widx = threadIdx.x >> 6;
  int lane = threadIdx.x & 63;
  int i = blockIdx.x * 4 + widx;
  if (i >= M) return;
  const float* fr = fc + (size_t)i * 128;
  rowbuf[widx][lane]      = fmaxf(fr[lane], 0.f);
  rowbuf[widx][lane + 64] = fmaxf(fr[lane + 64], 0.f);
  float acc = bout[lane];
#pragma unroll 8
  for (int k = 0; k < 128; ++k) acc += rowbuf[widx][k] * Wout[k * 64 + lane];
  out[(size_t)i * 64 + lane] = acc;
}

// ---------------------------------------------------------------------------

static void build_csr(const int* src, const int* dst, int E, int N,
                      int* off, int* srcs, int* cur, int* bsum, hipStream_t stream)
{
  const int nb = (N + 1023) / 1024;
  deg_init_k<<<dim3((N + 255) / 256), 256, 0, stream>>>(cur, off, N, E + N);
  deg_k<<<dim3((E + 255) / 256), 256, 0, stream>>>(dst, cur, E);
  scan1_k<<<dim3(nb), 256, 0, stream>>>(cur, off, bsum, N);
  scan2_k<<<dim3(1), 256, 0, stream>>>(bsum, nb);
  scan3_k<<<dim3((N + 255) / 256), 256, 0, stream>>>(off, bsum, N);
  fill_self_k<<<dim3((N + 255) / 256), 256, 0, stream>>>(off, srcs, cur, N);
  fill_edge_k<<<dim3((E + 255) / 256), 256, 0, stream>>>(src, dst, off, cur, srcs, E);
}

static void run_gat_layer(const float* in, int relu_in, const float* W,
                          const float* a_s, const float* a_d, const float* b,
                          const int* off, const int* srcs, int N,
                          float* h, float* es, float* ed, float* out, hipStream_t stream)
{
  gemm_k<<<dim3((N + 63) / 64), 256, 0, stream>>>(in, W, nullptr, a_s, a_d, h, es, ed, N, 128, relu_in);
  gat_aggr_k<<<dim3((N + 3) / 4), 256, 0, stream>>>(off, srcs, es, ed, h, b, out, N);
}

extern "C" void kernel_launch(void* const* d_in, const int* in_sizes, int n_in,
                              void* d_out, int out_size, void* d_ws, size_t ws_size,
                              hipStream_t stream)
{
  const float* x    = (const float*)d_in[0];
  const int*   eix  = (const int*)d_in[1];
  const int*   eiy  = (const int*)d_in[2];
  const int*   idx  = (const int*)d_in[3];
  const float* Wx1  = (const float*)d_in[4];
  const float* asx1 = (const float*)d_in[5];
  const float* adx1 = (const float*)d_in[6];
  const float* bx1  = (const float*)d_in[7];
  const float* Wx2  = (const float*)d_in[8];
  const float* asx2 = (const float*)d_in[9];
  const float* adx2 = (const float*)d_in[10];
  const float* bx2  = (const float*)d_in[11];
  const float* Wy1  = (const float*)d_in[12];
  const float* asy1 = (const float*)d_in[13];
  const float* ady1 = (const float*)d_in[14];
  const float* by1  = (const float*)d_in[15];
  const float* Wy2  = (const float*)d_in[16];
  const float* asy2 = (const float*)d_in[17];
  const float* ady2 = (const float*)d_in[18];
  const float* by2  = (const float*)d_in[19];
  const float* Wfc  = (const float*)d_in[20];
  const float* bfc  = (const float*)d_in[21];
  const float* Wout = (const float*)d_in[22];
  const float* bout = (const float*)d_in[23];

  const int N    = in_sizes[0] / 128;   // 50000
  const int E    = in_sizes[1] / 2;     // 600000
  const int Midx = in_sizes[3];         // 10000

  const int* srcx = eix;
  const int* dstx = eix + E;
  const int* srcy = eiy;
  const int* dsty = eiy + E;

  // workspace layout
  char* wsb = (char*)d_ws;
  const size_t NB = (size_t)N * 128 * 4;          // 25.6 MB
  float* hbuf  = (float*)(wsb);
  float* inter = (float*)(wsb + NB);
  float* hx    = (float*)(wsb + 2 * NB);
  float* hy    = (float*)(wsb + 3 * NB);
  char*  p     = wsb + 4 * NB;
  float* es    = (float*)p;            p += (size_t)N * 4;
  float* ed    = (float*)p;            p += (size_t)N * 4;
  int*   offx  = (int*)p;              p += (size_t)(N + 1) * 4;
  int*   offy  = (int*)p;              p += (size_t)(N + 1) * 4;
  int*   cur   = (int*)p;              p += (size_t)N * 4;
  int*   bsum  = (int*)p;              p += 256 * 4;
  int*   srcxs = (int*)p;              p += (size_t)(E + N) * 4;
  int*   srcys = (int*)p;              p += (size_t)(E + N) * 4;

  build_csr(srcx, dstx, E, N, offx, srcxs, cur, bsum, stream);
  build_csr(srcy, dsty, E, N, offy, srcys, cur, bsum, stream);

  // x branch
  run_gat_layer(x,     0, Wx1, asx1, adx1, bx1, offx, srcxs, N, hbuf, es, ed, inter, stream);
  run_gat_layer(inter, 1, Wx2, asx2, adx2, bx2, offx, srcxs, N, hbuf, es, ed, hx,    stream);
  // y branch
  run_gat_layer(x,     0, Wy1, asy1, ady1, by1, offy, srcys, N, hbuf, es, ed, inter, stream);
  run_gat_layer(inter, 1, Wy2, asy2, ady2, by2, offy, srcys, N, hbuf, es, ed, hy,    stream);

  // head: only the 10000 indexed rows
  float* fcbuf = hbuf;            // 10000 x 256 (reuse)
  float* fcout = inter;           // 10000 x 128 (reuse)
  gather_k<<<dim3((Midx * 256 + 255) / 256), 256, 0, stream>>>(idx, hx, hy, fcbuf, Midx);
  gemm_k<<<dim3((Midx + 63) / 64), 256, 0, stream>>>(fcbuf, Wfc, bfc, nullptr, nullptr, fcout, nullptr, nullptr, Midx, 256, 0);
  head_k<<<dim3((Midx + 3) / 4), 256, 0, stream>>>(fcout, Wout, bout, (float*)d_out, Midx);
}

// Round 6
// 499.088 us; speedup vs baseline: 1.1279x; 1.1279x over previous
//
#include <hip/hip_runtime.h>

// ---------------------------------------------------------------------------
// GAT (heads=1) x2 layers x2 branches + FC head.
// R6: h stored as bf16 (RNE) by the GEMM; aggregation gathers bf16 rows
// (halves the capacity-miss traffic that dominates gat_aggr_k). All
// accumulation / layer outputs / softmax / head remain fp32.
// Aggr gather pipeline back to 8-deep (R5's 16-deep cost occupancy).
// Softmax without max pass (shift-invariant; self-loops guarantee nonempty
// segments; |logits| small).
// ---------------------------------------------------------------------------

// bijective LDS swizzle on float4-group index (0..31): xor bit0 with bit3
__device__ __forceinline__ int wswz(int g) { return g ^ ((g >> 3) & 1); }

__device__ __forceinline__ unsigned bf16rne(float x) {
  unsigned u = __float_as_uint(x);
  return (u + 0x7fffu + ((u >> 16) & 1u)) >> 16;
}
__device__ __forceinline__ unsigned pack2(float lo, float hi) {
  return bf16rne(lo) | (bf16rne(hi) << 16);
}

// C[M,128] = (relu_in? relu(A) : A)[M,K] @ W[K,128] (+ bias)
// Output: fp32 to Cf if non-null, else packed bf16 (2/uint) to Cb.
// If a_s != nullptr: also es[row] = C_row · a_s, ed[row] = C_row · a_d.
__global__ __launch_bounds__(256) void gemm_k(
    const float* __restrict__ A, const float* __restrict__ W,
    const float* __restrict__ bias,
    const float* __restrict__ a_s, const float* __restrict__ a_d,
    float* __restrict__ Cf, unsigned* __restrict__ Cb,
    float* __restrict__ es, float* __restrict__ ed,
    int M, int K, int relu_in)
{
  __shared__ float Ast[32][68];     // [kk][row], pad 68: b128 frag reads conflict-free
  __shared__ float Ws[32][128];     // [kk][swizzled float4 groups]
  const int tid = threadIdx.x;
  const int bm  = blockIdx.x * 64;
  const int tc  = tid & 15;
  const int tr  = tid >> 4;

  float acc[4][8];
#pragma unroll
  for (int r = 0; r < 4; ++r)
#pragma unroll
    for (int c = 0; c < 8; ++c) acc[r][c] = 0.f;

  const int T = K >> 5;
  float4 areg[2], wreg[4];

  auto load_regs = [&](int k0) {
#pragma unroll
    for (int t = 0; t < 2; ++t) {
      int v   = tid + t * 256;
      int row = v >> 3;
      int kq  = (v & 7) * 4;
      float4 av = make_float4(0.f, 0.f, 0.f, 0.f);
      if (bm + row < M)
        av = *reinterpret_cast<const float4*>(A + (size_t)(bm + row) * K + k0 + kq);
      if (relu_in) {
        av.x = fmaxf(av.x, 0.f); av.y = fmaxf(av.y, 0.f);
        av.z = fmaxf(av.z, 0.f); av.w = fmaxf(av.w, 0.f);
      }
      areg[t] = av;
    }
#pragma unroll
    for (int t = 0; t < 4; ++t) {
      int v  = tid + t * 256;
      int kr = v >> 5;
      int nq = (v & 31) * 4;
      wreg[t] = *reinterpret_cast<const float4*>(W + (size_t)(k0 + kr) * 128 + nq);
    }
  };
  auto write_lds = [&]() {
#pragma unroll
    for (int t = 0; t < 2; ++t) {
      int v   = tid + t * 256;
      int row = v >> 3;
      int kq  = (v & 7) * 4;
      Ast[kq + 0][row] = areg[t].x;
      Ast[kq + 1][row] = areg[t].y;
      Ast[kq + 2][row] = areg[t].z;
      Ast[kq + 3][row] = areg[t].w;
    }
#pragma unroll
    for (int t = 0; t < 4; ++t) {
      int v  = tid + t * 256;
      int kr = v >> 5;
      int g  = v & 31;                       // float4 group index
      *reinterpret_cast<float4*>(&Ws[kr][wswz(g) * 4]) = wreg[t];
    }
  };

  // ---- pipelined K loop (single LDS buffer, 2 barriers/tile) ----
  load_regs(0);
  write_lds();
  __syncthreads();
  for (int t = 0;; ++t) {
    if (t + 1 < T) load_regs((t + 1) * 32);   // global loads in flight across compute

#pragma unroll 8
    for (int kk = 0; kk < 32; ++kk) {
      float4 a4 = *reinterpret_cast<const float4*>(&Ast[kk][tr * 4]);
      float4 w0 = *reinterpret_cast<const float4*>(&Ws[kk][wswz(tc * 2) * 4]);
      float4 w1 = *reinterpret_cast<const float4*>(&Ws[kk][wswz(tc * 2 + 1) * 4]);
      float a[4] = {a4.x, a4.y, a4.z, a4.w};
      float w[8] = {w0.x, w0.y, w0.z, w0.w, w1.x, w1.y, w1.z, w1.w};
#pragma unroll
      for (int r = 0; r < 4; ++r)
#pragma unroll
        for (int c = 0; c < 8; ++c) acc[r][c] += a[r] * w[c];
    }

    if (t + 1 >= T) break;
    __syncthreads();     // everyone done reading LDS
    write_lds();         // waits on the in-flight global loads
    __syncthreads();
  }

  // ---- C write (fp32 or packed bf16) ----
#pragma unroll
  for (int r = 0; r < 4; ++r) {
    int row = bm + tr * 4 + r;
    if (row >= M) continue;
    float b[8] = {0.f,0.f,0.f,0.f,0.f,0.f,0.f,0.f};
    if (bias) {
#pragma unroll
      for (int c = 0; c < 8; ++c) b[c] = bias[tc * 8 + c];
    }
    if (Cf) {
      float4 o0 = make_float4(acc[r][0] + b[0], acc[r][1] + b[1], acc[r][2] + b[2], acc[r][3] + b[3]);
      float4 o1 = make_float4(acc[r][4] + b[4], acc[r][5] + b[5], acc[r][6] + b[6], acc[r][7] + b[7]);
      *reinterpret_cast<float4*>(Cf + (size_t)row * 128 + tc * 8)     = o0;
      *reinterpret_cast<float4*>(Cf + (size_t)row * 128 + tc * 8 + 4) = o1;
    } else {
      uint4 u;
      u.x = pack2(acc[r][0] + b[0], acc[r][1] + b[1]);
      u.y = pack2(acc[r][2] + b[2], acc[r][3] + b[3]);
      u.z = pack2(acc[r][4] + b[4], acc[r][5] + b[5]);
      u.w = pack2(acc[r][6] + b[6], acc[r][7] + b[7]);
      *reinterpret_cast<uint4*>(Cb + (size_t)row * 64 + tc * 4) = u;
    }
  }

  // ---- fused attn epilogue: es/ed per row (from fp32 acc) ----
  if (a_s) {
    float asv[8], adv[8];
#pragma unroll
    for (int c = 0; c < 8; ++c) { asv[c] = a_s[tc * 8 + c]; adv[c] = a_d[tc * 8 + c]; }
#pragma unroll
    for (int r = 0; r < 4; ++r) {
      float ps = 0.f, pd = 0.f;
#pragma unroll
      for (int c = 0; c < 8; ++c) { ps += acc[r][c] * asv[c]; pd += acc[r][c] * adv[c]; }
#pragma unroll
      for (int o = 1; o < 16; o <<= 1) {
        ps += __shfl_xor(ps, o, 64);
        pd += __shfl_xor(pd, o, 64);
      }
      int row = bm + tr * 4 + r;
      if (tc == 0 && row < M) { es[row] = ps; ed[row] = pd; }
    }
  }
}

// ---------------- CSR build (by dst, self-loop at slot off[i]) ----------------

__global__ __launch_bounds__(256) void deg_init_k(int* __restrict__ deg, int* __restrict__ off, int N, int total)
{
  int i = blockIdx.x * 256 + threadIdx.x;
  if (i < N) deg[i] = 1;                 // self loop
  if (i == 0) off[N] = total;
}

__global__ __launch_bounds__(256) void deg_k(const int* __restrict__ dst, int* __restrict__ deg, int E)
{
  int e = blockIdx.x * 256 + threadIdx.x;
  if (e < E) atomicAdd(&deg[dst[e]], 1);
}

// exclusive scan, 1024 elements per block (4/thread)
__global__ __launch_bounds__(256) void scan1_k(
    const int* __restrict__ deg, int* __restrict__ off, int* __restrict__ bsum, int N)
{
  __shared__ int ts[256];
  int base = blockIdx.x * 1024 + threadIdx.x * 4;
  int v[4]; int s = 0;
#pragma unroll
  for (int t = 0; t < 4; ++t) { v[t] = (base + t < N) ? deg[base + t] : 0; s += v[t]; }
  ts[threadIdx.x] = s;
  __syncthreads();
  int mine = s;
#pragma unroll
  for (int o = 1; o < 256; o <<= 1) {
    int x = (threadIdx.x >= o) ? ts[threadIdx.x - o] : 0;
    __syncthreads();
    ts[threadIdx.x] += x;
    __syncthreads();
  }
  int run = ts[threadIdx.x] - mine;
#pragma unroll
  for (int t = 0; t < 4; ++t) {
    if (base + t < N) off[base + t] = run;
    run += v[t];
  }
  if (threadIdx.x == 255) bsum[blockIdx.x] = ts[255];
}

__global__ __launch_bounds__(256) void scan2_k(int* __restrict__ bsum, int nb)
{
  __shared__ int ts[256];
  int v = (threadIdx.x < nb) ? bsum[threadIdx.x] : 0;
  ts[threadIdx.x] = v;
  __syncthreads();
  int mine = v;
#pragma unroll
  for (int o = 1; o < 256; o <<= 1) {
    int x = (threadIdx.x >= o) ? ts[threadIdx.x - o] : 0;
    __syncthreads();
    ts[threadIdx.x] += x;
    __syncthreads();
  }
  if (threadIdx.x < nb) bsum[threadIdx.x] = ts[threadIdx.x] - mine;
}

__global__ __launch_bounds__(256) void scan3_k(int* __restrict__ off, const int* __restrict__ bsum, int N)
{
  int i = blockIdx.x * 256 + threadIdx.x;
  if (i < N) off[i] += bsum[i >> 10];
}

__global__ __launch_bounds__(256) void fill_self_k(
    const int* __restrict__ off, int* __restrict__ srcs, int* __restrict__ cur, int N)
{
  int i = blockIdx.x * 256 + threadIdx.x;
  if (i < N) { srcs[off[i]] = i; cur[i] = 1; }
}

__global__ __launch_bounds__(256) void fill_edge_k(
    const int* __restrict__ src, const int* __restrict__ dst,
    const int* __restrict__ off, int* __restrict__ cur, int* __restrict__ srcs, int E)
{
  int e = blockIdx.x * 256 + threadIdx.x;
  if (e < E) {
    int d = dst[e];
    int j = off[d] + atomicAdd(&cur[d], 1);
    srcs[j] = src[e];
  }
}

// ---------------- fused per-node softmax + aggregate (one wave per node) -----
// h is packed bf16 (64 uints/row). Per 64-edge chunk: lanes compute p in
// parallel; aggregation pulls (s,p) via shfl, 8 bf16-row loads in flight.
__global__ __launch_bounds__(256) void gat_aggr_k(
    const int* __restrict__ off, const int* __restrict__ srcs,
    const float* __restrict__ es, const float* __restrict__ ed,
    const unsigned* __restrict__ h, const float* __restrict__ bias,
    float* __restrict__ out, int N)
{
  int w    = (blockIdx.x * 256 + threadIdx.x) >> 6;
  int lane = threadIdx.x & 63;
  if (w >= N) return;
  int b  = off[w];
  int e2 = off[w + 1];
  float edv = ed[w];
  float ax = 0.f, ay = 0.f, dsum = 0.f;

  for (int c0 = b; c0 < e2; c0 += 64) {
    int nc = e2 - c0; if (nc > 64) nc = 64;
    int  sl = srcs[c0 + (lane < nc ? lane : 0)];
    float pl = 0.f;
    if (lane < nc) {
      float l = es[sl] + edv;
      l = (l > 0.f) ? l : 0.2f * l;
      pl = expf(l);
    }
    dsum += pl;

    for (int e = 0; e < nc; e += 8) {
      unsigned hv[8]; float pp[8];
#pragma unroll
      for (int k = 0; k < 8; ++k) {
        int  ok  = (e + k) < nc;
        int  idx = ok ? (e + k) : 0;
        int  s   = __shfl(sl, idx, 64);
        pp[k]    = ok ? __shfl(pl, idx, 64) : 0.f;
        hv[k]    = h[(size_t)s * 64 + lane];
      }
#pragma unroll
      for (int k = 0; k < 8; ++k) {
        float hx = __uint_as_float(hv[k] << 16);
        float hy = __uint_as_float(hv[k] & 0xffff0000u);
        ax += pp[k] * hx;
        ay += pp[k] * hy;
      }
    }
  }

#pragma unroll
  for (int o = 32; o > 0; o >>= 1) dsum += __shfl_xor(dsum, o, 64);
  float inv = 1.f / dsum;
  float2 o2 = make_float2(ax * inv + bias[lane * 2], ay * inv + bias[lane * 2 + 1]);
  *reinterpret_cast<float2*>(out + (size_t)w * 128 + lane * 2) = o2;
}

// fcbuf[i, 0:128] = relu(hx[idx[i]]), [128:256] = relu(hy[idx[i]])
__global__ __launch_bounds__(256) void gather_k(
    const int* __restrict__ idx, const float* __restrict__ hx,
    const float* __restrict__ hy, float* __restrict__ outb, int M)
{
  int t = blockIdx.x * 256 + threadIdx.x;
  if (t >= M * 256) return;
  int i = t >> 8, c = t & 255;
  int r = idx[i];
  float v = (c < 128) ? hx[(size_t)r * 128 + c] : hy[(size_t)r * 128 + (c - 128)];
  outb[t] = fmaxf(v, 0.f);
}

// out[i, 0:64] = relu(fc[i,:]) @ Wout[128,64] + bout   (one wave per row)
__global__ __launch_bounds__(256) void head_k(
    const float* __restrict__ fc, const float* __restrict__ Wout,
    const float* __restrict__ bout, float* __restrict__ out, int M)
{
  __shared__ float rowbuf[4][128];
  int widx = threadIdx.x >> 6;
  int lane = threadIdx.x & 63;
  int i = blockIdx.x * 4 + widx;
  if (i >= M) return;
  const float* fr = fc + (size_t)i * 128;
  rowbuf[widx][lane]      = fmaxf(fr[lane], 0.f);
  rowbuf[widx][lane + 64] = fmaxf(fr[lane + 64], 0.f);
  float acc = bout[lane];
#pragma unroll 8
  for (int k = 0; k < 128; ++k) acc += rowbuf[widx][k] * Wout[k * 64 + lane];
  out[(size_t)i * 64 + lane] = acc;
}

// ---------------------------------------------------------------------------

static void build_csr(const int* src, const int* dst, int E, int N,
                      int* off, int* srcs, int* cur, int* bsum, hipStream_t stream)
{
  const int nb = (N + 1023) / 1024;
  deg_init_k<<<dim3((N + 255) / 256), 256, 0, stream>>>(cur, off, N, E + N);
  deg_k<<<dim3((E + 255) / 256), 256, 0, stream>>>(dst, cur, E);
  scan1_k<<<dim3(nb), 256, 0, stream>>>(cur, off, bsum, N);
  scan2_k<<<dim3(1), 256, 0, stream>>>(bsum, nb);
  scan3_k<<<dim3((N + 255) / 256), 256, 0, stream>>>(off, bsum, N);
  fill_self_k<<<dim3((N + 255) / 256), 256, 0, stream>>>(off, srcs, cur, N);
  fill_edge_k<<<dim3((E + 255) / 256), 256, 0, stream>>>(src, dst, off, cur, srcs, E);
}

static void run_gat_layer(const float* in, int relu_in, const float* W,
                          const float* a_s, const float* a_d, const float* b,
                          const int* off, const int* srcs, int N,
                          unsigned* hbf, float* es, float* ed, float* out, hipStream_t stream)
{
  gemm_k<<<dim3((N + 63) / 64), 256, 0, stream>>>(in, W, nullptr, a_s, a_d,
                                                  nullptr, hbf, es, ed, N, 128, relu_in);
  gat_aggr_k<<<dim3((N + 3) / 4), 256, 0, stream>>>(off, srcs, es, ed, hbf, b, out, N);
}

extern "C" void kernel_launch(void* const* d_in, const int* in_sizes, int n_in,
                              void* d_out, int out_size, void* d_ws, size_t ws_size,
                              hipStream_t stream)
{
  const float* x    = (const float*)d_in[0];
  const int*   eix  = (const int*)d_in[1];
  const int*   eiy  = (const int*)d_in[2];
  const int*   idx  = (const int*)d_in[3];
  const float* Wx1  = (const float*)d_in[4];
  const float* asx1 = (const float*)d_in[5];
  const float* adx1 = (const float*)d_in[6];
  const float* bx1  = (const float*)d_in[7];
  const float* Wx2  = (const float*)d_in[8];
  const float* asx2 = (const float*)d_in[9];
  const float* adx2 = (const float*)d_in[10];
  const float* bx2  = (const float*)d_in[11];
  const float* Wy1  = (const float*)d_in[12];
  const float* asy1 = (const float*)d_in[13];
  const float* ady1 = (const float*)d_in[14];
  const float* by1  = (const float*)d_in[15];
  const float* Wy2  = (const float*)d_in[16];
  const float* asy2 = (const float*)d_in[17];
  const float* ady2 = (const float*)d_in[18];
  const float* by2  = (const float*)d_in[19];
  const float* Wfc  = (const float*)d_in[20];
  const float* bfc  = (const float*)d_in[21];
  const float* Wout = (const float*)d_in[22];
  const float* bout = (const float*)d_in[23];

  const int N    = in_sizes[0] / 128;   // 50000
  const int E    = in_sizes[1] / 2;     // 600000
  const int Midx = in_sizes[3];         // 10000

  const int* srcx = eix;
  const int* dstx = eix + E;
  const int* srcy = eiy;
  const int* dsty = eiy + E;

  // workspace layout
  char* wsb = (char*)d_ws;
  const size_t NB = (size_t)N * 128 * 4;          // 25.6 MB (fp32 node buf)
  unsigned* hbf  = (unsigned*)(wsb);              // bf16 h, 12.8 MB (in 25.6 slot)
  float* inter = (float*)(wsb + NB);
  float* hx    = (float*)(wsb + 2 * NB);
  float* hy    = (float*)(wsb + 3 * NB);
  char*  p     = wsb + 4 * NB;
  float* es    = (float*)p;            p += (size_t)N * 4;
  float* ed    = (float*)p;            p += (size_t)N * 4;
  int*   offx  = (int*)p;              p += (size_t)(N + 1) * 4;
  int*   offy  = (int*)p;              p += (size_t)(N + 1) * 4;
  int*   cur   = (int*)p;              p += (size_t)N * 4;
  int*   bsum  = (int*)p;              p += 256 * 4;
  int*   srcxs = (int*)p;              p += (size_t)(E + N) * 4;
  int*   srcys = (int*)p;              p += (size_t)(E + N) * 4;

  build_csr(srcx, dstx, E, N, offx, srcxs, cur, bsum, stream);
  build_csr(srcy, dsty, E, N, offy, srcys, cur, bsum, stream);

  // x branch
  run_gat_layer(x,     0, Wx1, asx1, adx1, bx1, offx, srcxs, N, hbf, es, ed, inter, stream);
  run_gat_layer(inter, 1, Wx2, asx2, adx2, bx2, offx, srcxs, N, hbf, es, ed, hx,    stream);
  // y branch
  run_gat_layer(x,     0, Wy1, asy1, ady1, by1, offy, srcys, N, hbf, es, ed, inter, stream);
  run_gat_layer(inter, 1, Wy2, asy2, ady2, by2, offy, srcys, N, hbf, es, ed, hy,    stream);

  // head: only the 10000 indexed rows
  float* fcbuf = (float*)hbf;     // 10000 x 256 fp32 (reuse, 10.24 MB)
  float* fcout = inter;           // 10000 x 128 fp32 (reuse)
  gather_k<<<dim3((Midx * 256 + 255) / 256), 256, 0, stream>>>(idx, hx, hy, fcbuf, Midx);
  gemm_k<<<dim3((Midx + 63) / 64), 256, 0, stream>>>(fcbuf, Wfc, bfc, nullptr, nullptr,
                                                     fcout, nullptr, nullptr, nullptr, Midx, 256, 0);
  head_k<<<dim3((Midx + 3) / 4), 256, 0, stream>>>(fcout, Wout, bout, (float*)d_out, Midx);
}

// Round 7
// 438.895 us; speedup vs baseline: 1.2826x; 1.1371x over previous
//
#include <hip/hip_runtime.h>

// ---------------------------------------------------------------------------
// GAT (heads=1) x2 layers x2 branches + FC head.
// R7: layer GEMMs -> LDS-free bf16 MFMA (16x16x32), fp32 accum.
//   - W pre-packed once/layer into B-fragment layout (bf16) by wprep_k.
//   - A-fragments loaded straight from global fp32, converted in-register.
//   - es/ed kept EXACT fp32 via ws = W@a_s precompute: es = A_fp32 . ws,
//     fused into the A-load (softmax logits carry no bf16 error).
//   - h written as bf16 (ushort) for the capacity-bound aggregation gather.
// Head/FC stays on the fp32 VALU gemm_k. Softmax without max pass
// (shift-invariant; self-loops guarantee nonempty segments).
// ---------------------------------------------------------------------------

typedef __attribute__((ext_vector_type(8))) short bf16x8;
typedef __attribute__((ext_vector_type(4))) float f32x4;

__device__ __forceinline__ unsigned bf16rne(float x) {
  unsigned u = __float_as_uint(x);
  return (u + 0x7fffu + ((u >> 16) & 1u)) >> 16;
}
__device__ __forceinline__ unsigned pack2(float lo, float hi) {
  return bf16rne(lo) | (bf16rne(hi) << 16);
}
// bijective LDS swizzle on float4-group index (0..31): xor bit0 with bit3
__device__ __forceinline__ int wswz(int g) { return g ^ ((g >> 3) & 1); }

// ---------------- W prep: fragment packing + ws = W @ a ----------------------
// B-frag layout for v_mfma_f32_16x16x32_bf16: lane l supplies
// B[k = kt*32 + (l>>4)*8 + i][col = ct*16 + (l&15)], i=0..7.
// wfrag element index = ((kt*8 + ct)*64 + lane)*8 + i.
__global__ __launch_bounds__(256) void wprep_k(
    const float* __restrict__ W, ushort* __restrict__ wfrag, int K)
{
  int e = blockIdx.x * 256 + threadIdx.x;
  if (e >= K * 128) return;
  int i    = e & 7;
  int lane = (e >> 3) & 63;
  int ct   = (e >> 9) & 7;
  int kt   = e >> 12;
  int k    = kt * 32 + ((lane >> 4) << 3) + i;
  int col  = ct * 16 + (lane & 15);
  wfrag[e] = (ushort)bf16rne(W[(size_t)k * 128 + col]);
}

__global__ __launch_bounds__(128) void wsprep_k(
    const float* __restrict__ W, const float* __restrict__ a_s,
    const float* __restrict__ a_d, float* __restrict__ ws_s,
    float* __restrict__ ws_d, int K)
{
  int k = blockIdx.x * 128 + threadIdx.x;
  if (k >= K) return;
  float s = 0.f, d = 0.f;
  for (int c = 0; c < 128; ++c) {
    float w = W[(size_t)k * 128 + c];
    s += w * a_s[c];
    d += w * a_d[c];
  }
  ws_s[k] = s; ws_d[k] = d;
}

// ---------------- MFMA GEMM: h(bf16) = (relu?) A(fp32) @ W, es/ed fp32 -------
// block = 256 thr = 4 waves; wave w owns rows [bid*64 + w*16, +16), all 128 cols.
__global__ __launch_bounds__(256) void mgemm_k(
    const float* __restrict__ A, const ushort* __restrict__ wfrag,
    const float* __restrict__ ws_s, const float* __restrict__ ws_d,
    ushort* __restrict__ Cb, float* __restrict__ es, float* __restrict__ ed,
    int M, int K, int relu_in)
{
  const int tid = threadIdx.x;
  const int w   = tid >> 6;
  const int l   = tid & 63;
  const int rowbase = blockIdx.x * 64 + w * 16;
  const int arow    = rowbase + (l & 15);
  const bool valid  = arow < M;
  const int kofs    = (l >> 4) * 8;
  const float* Ap   = A + (size_t)arow * K + kofs;

  f32x4 acc[8];
#pragma unroll
  for (int ct = 0; ct < 8; ++ct) acc[ct] = (f32x4){0.f, 0.f, 0.f, 0.f};
  float esp = 0.f, edp = 0.f;

  const int T = K >> 5;
  for (int kt = 0; kt < T; ++kt) {
    float4 a0 = make_float4(0.f, 0.f, 0.f, 0.f), a1 = a0;
    if (valid) {
      a0 = *reinterpret_cast<const float4*>(Ap + kt * 32);
      a1 = *reinterpret_cast<const float4*>(Ap + kt * 32 + 4);
    }
    if (relu_in) {
      a0.x = fmaxf(a0.x, 0.f); a0.y = fmaxf(a0.y, 0.f);
      a0.z = fmaxf(a0.z, 0.f); a0.w = fmaxf(a0.w, 0.f);
      a1.x = fmaxf(a1.x, 0.f); a1.y = fmaxf(a1.y, 0.f);
      a1.z = fmaxf(a1.z, 0.f); a1.w = fmaxf(a1.w, 0.f);
    }
    // exact fp32 attention-logit partials: es = A . (W@a_s)
    {
      float4 s0 = *reinterpret_cast<const float4*>(ws_s + kt * 32 + kofs);
      float4 s1 = *reinterpret_cast<const float4*>(ws_s + kt * 32 + kofs + 4);
      float4 d0 = *reinterpret_cast<const float4*>(ws_d + kt * 32 + kofs);
      float4 d1 = *reinterpret_cast<const float4*>(ws_d + kt * 32 + kofs + 4);
      esp += a0.x*s0.x + a0.y*s0.y + a0.z*s0.z + a0.w*s0.w
           + a1.x*s1.x + a1.y*s1.y + a1.z*s1.z + a1.w*s1.w;
      edp += a0.x*d0.x + a0.y*d0.y + a0.z*d0.z + a0.w*d0.w
           + a1.x*d1.x + a1.y*d1.y + a1.z*d1.z + a1.w*d1.w;
    }
    bf16x8 af;
    af[0] = (short)bf16rne(a0.x); af[1] = (short)bf16rne(a0.y);
    af[2] = (short)bf16rne(a0.z); af[3] = (short)bf16rne(a0.w);
    af[4] = (short)bf16rne(a1.x); af[5] = (short)bf16rne(a1.y);
    af[6] = (short)bf16rne(a1.z); af[7] = (short)bf16rne(a1.w);
#pragma unroll
    for (int ct = 0; ct < 8; ++ct) {
      bf16x8 bf = *reinterpret_cast<const bf16x8*>(
          wfrag + (((size_t)(kt * 8 + ct) * 64 + l) << 3));
      acc[ct] = __builtin_amdgcn_mfma_f32_16x16x32_bf16(af, bf, acc[ct], 0, 0, 0);
    }
  }

  // C write (bf16): C/D layout col = l&15, row = (l>>4)*4 + reg
  const int ccol  = l & 15;
  const int crow0 = rowbase + (l >> 4) * 4;
#pragma unroll
  for (int r = 0; r < 4; ++r) {
    int row = crow0 + r;
    if (row < M) {
#pragma unroll
      for (int ct = 0; ct < 8; ++ct)
        Cb[(size_t)row * 128 + ct * 16 + ccol] = (ushort)bf16rne(acc[ct][r]);
    }
  }

  // es/ed: reduce the 4 k-split lanes (same l&15, differing l>>4)
  esp += __shfl_xor(esp, 16, 64); esp += __shfl_xor(esp, 32, 64);
  edp += __shfl_xor(edp, 16, 64); edp += __shfl_xor(edp, 32, 64);
  if (l < 16 && valid) { es[arow] = esp; ed[arow] = edp; }
}

// ---------------- fp32 VALU GEMM (head/FC only) ------------------------------
__global__ __launch_bounds__(256) void gemm_k(
    const float* __restrict__ A, const float* __restrict__ W,
    const float* __restrict__ bias, float* __restrict__ Cf,
    int M, int K, int relu_in)
{
  __shared__ float Ast[32][68];
  __shared__ float Ws[32][128];
  const int tid = threadIdx.x;
  const int bm  = blockIdx.x * 64;
  const int tc  = tid & 15;
  const int tr  = tid >> 4;

  float acc[4][8];
#pragma unroll
  for (int r = 0; r < 4; ++r)
#pragma unroll
    for (int c = 0; c < 8; ++c) acc[r][c] = 0.f;

  const int T = K >> 5;
  float4 areg[2], wreg[4];

  auto load_regs = [&](int k0) {
#pragma unroll
    for (int t = 0; t < 2; ++t) {
      int v   = tid + t * 256;
      int row = v >> 3;
      int kq  = (v & 7) * 4;
      float4 av = make_float4(0.f, 0.f, 0.f, 0.f);
      if (bm + row < M)
        av = *reinterpret_cast<const float4*>(A + (size_t)(bm + row) * K + k0 + kq);
      if (relu_in) {
        av.x = fmaxf(av.x, 0.f); av.y = fmaxf(av.y, 0.f);
        av.z = fmaxf(av.z, 0.f); av.w = fmaxf(av.w, 0.f);
      }
      areg[t] = av;
    }
#pragma unroll
    for (int t = 0; t < 4; ++t) {
      int v  = tid + t * 256;
      int kr = v >> 5;
      int nq = (v & 31) * 4;
      wreg[t] = *reinterpret_cast<const float4*>(W + (size_t)(k0 + kr) * 128 + nq);
    }
  };
  auto write_lds = [&]() {
#pragma unroll
    for (int t = 0; t < 2; ++t) {
      int v   = tid + t * 256;
      int row = v >> 3;
      int kq  = (v & 7) * 4;
      Ast[kq + 0][row] = areg[t].x;
      Ast[kq + 1][row] = areg[t].y;
      Ast[kq + 2][row] = areg[t].z;
      Ast[kq + 3][row] = areg[t].w;
    }
#pragma unroll
    for (int t = 0; t < 4; ++t) {
      int v  = tid + t * 256;
      int kr = v >> 5;
      int g  = v & 31;
      *reinterpret_cast<float4*>(&Ws[kr][wswz(g) * 4]) = wreg[t];
    }
  };

  load_regs(0);
  write_lds();
  __syncthreads();
  for (int t = 0;; ++t) {
    if (t + 1 < T) load_regs((t + 1) * 32);
#pragma unroll 8
    for (int kk = 0; kk < 32; ++kk) {
      float4 a4 = *reinterpret_cast<const float4*>(&Ast[kk][tr * 4]);
      float4 w0 = *reinterpret_cast<const float4*>(&Ws[kk][wswz(tc * 2) * 4]);
      float4 w1 = *reinterpret_cast<const float4*>(&Ws[kk][wswz(tc * 2 + 1) * 4]);
      float a[4] = {a4.x, a4.y, a4.z, a4.w};
      float w[8] = {w0.x, w0.y, w0.z, w0.w, w1.x, w1.y, w1.z, w1.w};
#pragma unroll
      for (int r = 0; r < 4; ++r)
#pragma unroll
        for (int c = 0; c < 8; ++c) acc[r][c] += a[r] * w[c];
    }
    if (t + 1 >= T) break;
    __syncthreads();
    write_lds();
    __syncthreads();
  }

#pragma unroll
  for (int r = 0; r < 4; ++r) {
    int row = bm + tr * 4 + r;
    if (row >= M) continue;
    float b[8] = {0.f,0.f,0.f,0.f,0.f,0.f,0.f,0.f};
    if (bias) {
#pragma unroll
      for (int c = 0; c < 8; ++c) b[c] = bias[tc * 8 + c];
    }
    float4 o0 = make_float4(acc[r][0] + b[0], acc[r][1] + b[1], acc[r][2] + b[2], acc[r][3] + b[3]);
    float4 o1 = make_float4(acc[r][4] + b[4], acc[r][5] + b[5], acc[r][6] + b[6], acc[r][7] + b[7]);
    *reinterpret_cast<float4*>(Cf + (size_t)row * 128 + tc * 8)     = o0;
    *reinterpret_cast<float4*>(Cf + (size_t)row * 128 + tc * 8 + 4) = o1;
  }
}

// ---------------- CSR build (by dst, self-loop at slot off[i]) ----------------

__global__ __launch_bounds__(256) void deg_init_k(int* __restrict__ deg, int* __restrict__ off, int N, int total)
{
  int i = blockIdx.x * 256 + threadIdx.x;
  if (i < N) deg[i] = 1;
  if (i == 0) off[N] = total;
}

__global__ __launch_bounds__(256) void deg_k(const int* __restrict__ dst, int* __restrict__ deg, int E)
{
  int e = blockIdx.x * 256 + threadIdx.x;
  if (e < E) atomicAdd(&deg[dst[e]], 1);
}

__global__ __launch_bounds__(256) void scan1_k(
    const int* __restrict__ deg, int* __restrict__ off, int* __restrict__ bsum, int N)
{
  __shared__ int ts[256];
  int base = blockIdx.x * 1024 + threadIdx.x * 4;
  int v[4]; int s = 0;
#pragma unroll
  for (int t = 0; t < 4; ++t) { v[t] = (base + t < N) ? deg[base + t] : 0; s += v[t]; }
  ts[threadIdx.x] = s;
  __syncthreads();
  int mine = s;
#pragma unroll
  for (int o = 1; o < 256; o <<= 1) {
    int x = (threadIdx.x >= o) ? ts[threadIdx.x - o] : 0;
    __syncthreads();
    ts[threadIdx.x] += x;
    __syncthreads();
  }
  int run = ts[threadIdx.x] - mine;
#pragma unroll
  for (int t = 0; t < 4; ++t) {
    if (base + t < N) off[base + t] = run;
    run += v[t];
  }
  if (threadIdx.x == 255) bsum[blockIdx.x] = ts[255];
}

__global__ __launch_bounds__(256) void scan2_k(int* __restrict__ bsum, int nb)
{
  __shared__ int ts[256];
  int v = (threadIdx.x < nb) ? bsum[threadIdx.x] : 0;
  ts[threadIdx.x] = v;
  __syncthreads();
  int mine = v;
#pragma unroll
  for (int o = 1; o < 256; o <<= 1) {
    int x = (threadIdx.x >= o) ? ts[threadIdx.x - o] : 0;
    __syncthreads();
    ts[threadIdx.x] += x;
    __syncthreads();
  }
  if (threadIdx.x < nb) bsum[threadIdx.x] = ts[threadIdx.x] - mine;
}

__global__ __launch_bounds__(256) void scan3_k(int* __restrict__ off, const int* __restrict__ bsum, int N)
{
  int i = blockIdx.x * 256 + threadIdx.x;
  if (i < N) off[i] += bsum[i >> 10];
}

__global__ __launch_bounds__(256) void fill_self_k(
    const int* __restrict__ off, int* __restrict__ srcs, int* __restrict__ cur, int N)
{
  int i = blockIdx.x * 256 + threadIdx.x;
  if (i < N) { srcs[off[i]] = i; cur[i] = 1; }
}

__global__ __launch_bounds__(256) void fill_edge_k(
    const int* __restrict__ src, const int* __restrict__ dst,
    const int* __restrict__ off, int* __restrict__ cur, int* __restrict__ srcs, int E)
{
  int e = blockIdx.x * 256 + threadIdx.x;
  if (e < E) {
    int d = dst[e];
    int j = off[d] + atomicAdd(&cur[d], 1);
    srcs[j] = src[e];
  }
}

// ---------------- fused per-node softmax + aggregate (one wave per node) -----
__global__ __launch_bounds__(256) void gat_aggr_k(
    const int* __restrict__ off, const int* __restrict__ srcs,
    const float* __restrict__ es, const float* __restrict__ ed,
    const unsigned* __restrict__ h, const float* __restrict__ bias,
    float* __restrict__ out, int N)
{
  int w    = (blockIdx.x * 256 + threadIdx.x) >> 6;
  int lane = threadIdx.x & 63;
  if (w >= N) return;
  int b  = off[w];
  int e2 = off[w + 1];
  float edv = ed[w];
  float ax = 0.f, ay = 0.f, dsum = 0.f;

  for (int c0 = b; c0 < e2; c0 += 64) {
    int nc = e2 - c0; if (nc > 64) nc = 64;
    int  sl = srcs[c0 + (lane < nc ? lane : 0)];
    float pl = 0.f;
    if (lane < nc) {
      float l = es[sl] + edv;
      l = (l > 0.f) ? l : 0.2f * l;
      pl = expf(l);
    }
    dsum += pl;

    for (int e = 0; e < nc; e += 8) {
      unsigned hv[8]; float pp[8];
#pragma unroll
      for (int k = 0; k < 8; ++k) {
        int  ok  = (e + k) < nc;
        int  idx = ok ? (e + k) : 0;
        int  s   = __shfl(sl, idx, 64);
        pp[k]    = ok ? __shfl(pl, idx, 64) : 0.f;
        hv[k]    = h[(size_t)s * 64 + lane];
      }
#pragma unroll
      for (int k = 0; k < 8; ++k) {
        float hx = __uint_as_float(hv[k] << 16);
        float hy = __uint_as_float(hv[k] & 0xffff0000u);
        ax += pp[k] * hx;
        ay += pp[k] * hy;
      }
    }
  }

#pragma unroll
  for (int o = 32; o > 0; o >>= 1) dsum += __shfl_xor(dsum, o, 64);
  float inv = 1.f / dsum;
  float2 o2 = make_float2(ax * inv + bias[lane * 2], ay * inv + bias[lane * 2 + 1]);
  *reinterpret_cast<float2*>(out + (size_t)w * 128 + lane * 2) = o2;
}

// fcbuf[i, 0:128] = relu(hx[idx[i]]), [128:256] = relu(hy[idx[i]])
__global__ __launch_bounds__(256) void gather_k(
    const int* __restrict__ idx, const float* __restrict__ hx,
    const float* __restrict__ hy, float* __restrict__ outb, int M)
{
  int t = blockIdx.x * 256 + threadIdx.x;
  if (t >= M * 256) return;
  int i = t >> 8, c = t & 255;
  int r = idx[i];
  float v = (c < 128) ? hx[(size_t)r * 128 + c] : hy[(size_t)r * 128 + (c - 128)];
  outb[t] = fmaxf(v, 0.f);
}

// out[i, 0:64] = relu(fc[i,:]) @ Wout[128,64] + bout   (one wave per row)
__global__ __launch_bounds__(256) void head_k(
    const float* __restrict__ fc, const float* __restrict__ Wout,
    const float* __restrict__ bout, float* __restrict__ out, int M)
{
  __shared__ float rowbuf[4][128];
  int widx = threadIdx.x >> 6;
  int lane = threadIdx.x & 63;
  int i = blockIdx.x * 4 + widx;
  if (i >= M) return;
  const float* fr = fc + (size_t)i * 128;
  rowbuf[widx][lane]      = fmaxf(fr[lane], 0.f);
  rowbuf[widx][lane + 64] = fmaxf(fr[lane + 64], 0.f);
  float acc = bout[lane];
#pragma unroll 8
  for (int k = 0; k < 128; ++k) acc += rowbuf[widx][k] * Wout[k * 64 + lane];
  out[(size_t)i * 64 + lane] = acc;
}

// ---------------------------------------------------------------------------

static void build_csr(const int* src, const int* dst, int E, int N,
                      int* off, int* srcs, int* cur, int* bsum, hipStream_t stream)
{
  const int nb = (N + 1023) / 1024;
  deg_init_k<<<dim3((N + 255) / 256), 256, 0, stream>>>(cur, off, N, E + N);
  deg_k<<<dim3((E + 255) / 256), 256, 0, stream>>>(dst, cur, E);
  scan1_k<<<dim3(nb), 256, 0, stream>>>(cur, off, bsum, N);
  scan2_k<<<dim3(1), 256, 0, stream>>>(bsum, nb);
  scan3_k<<<dim3((N + 255) / 256), 256, 0, stream>>>(off, bsum, N);
  fill_self_k<<<dim3((N + 255) / 256), 256, 0, stream>>>(off, srcs, cur, N);
  fill_edge_k<<<dim3((E + 255) / 256), 256, 0, stream>>>(src, dst, off, cur, srcs, E);
}

static void run_gat_layer(const float* in, int relu_in,
                          const ushort* wfrag, const float* ws_s, const float* ws_d,
                          const float* b, const int* off, const int* srcs, int N,
                          ushort* hbf, float* es, float* ed, float* out, hipStream_t stream)
{
  mgemm_k<<<dim3((N + 63) / 64), 256, 0, stream>>>(in, wfrag, ws_s, ws_d,
                                                   hbf, es, ed, N, 128, relu_in);
  gat_aggr_k<<<dim3((N + 3) / 4), 256, 0, stream>>>(off, srcs, es, ed,
                                                    (const unsigned*)hbf, b, out, N);
}

extern "C" void kernel_launch(void* const* d_in, const int* in_sizes, int n_in,
                              void* d_out, int out_size, void* d_ws, size_t ws_size,
                              hipStream_t stream)
{
  const float* x    = (const float*)d_in[0];
  const int*   eix  = (const int*)d_in[1];
  const int*   eiy  = (const int*)d_in[2];
  const int*   idx  = (const int*)d_in[3];
  const float* Wx1  = (const float*)d_in[4];
  const float* asx1 = (const float*)d_in[5];
  const float* adx1 = (const float*)d_in[6];
  const float* bx1  = (const float*)d_in[7];
  const float* Wx2  = (const float*)d_in[8];
  const float* asx2 = (const float*)d_in[9];
  const float* adx2 = (const float*)d_in[10];
  const float* bx2  = (const float*)d_in[11];
  const float* Wy1  = (const float*)d_in[12];
  const float* asy1 = (const float*)d_in[13];
  const float* ady1 = (const float*)d_in[14];
  const float* by1  = (const float*)d_in[15];
  const float* Wy2  = (const float*)d_in[16];
  const float* asy2 = (const float*)d_in[17];
  const float* ady2 = (const float*)d_in[18];
  const float* by2  = (const float*)d_in[19];
  const float* Wfc  = (const float*)d_in[20];
  const float* bfc  = (const float*)d_in[21];
  const float* Wout = (const float*)d_in[22];
  const float* bout = (const float*)d_in[23];

  const int N    = in_sizes[0] / 128;   // 50000
  const int E    = in_sizes[1] / 2;     // 600000
  const int Midx = in_sizes[3];         // 10000

  const int* srcx = eix;
  const int* dstx = eix + E;
  const int* srcy = eiy;
  const int* dsty = eiy + E;

  // workspace layout
  char* wsb = (char*)d_ws;
  const size_t NB = (size_t)N * 128 * 4;          // 25.6 MB (fp32 node buf)
  ushort* hbf  = (ushort*)(wsb);                  // bf16 h (12.8 MB in 25.6 slot)
  float* inter = (float*)(wsb + NB);
  float* hx    = (float*)(wsb + 2 * NB);
  float* hy    = (float*)(wsb + 3 * NB);
  char*  p     = wsb + 4 * NB;
  float* es    = (float*)p;            p += (size_t)N * 4;
  float* ed    = (float*)p;            p += (size_t)N * 4;
  int*   offx  = (int*)p;              p += (size_t)(N + 1) * 4;
  int*   offy  = (int*)p;              p += (size_t)(N + 1) * 4;
  int*   cur   = (int*)p;              p += (size_t)N * 4;
  int*   bsum  = (int*)p;              p += 256 * 4;
  int*   srcxs = (int*)p;              p += (size_t)(E + N) * 4;
  int*   srcys = (int*)p;              p += (size_t)(E + N) * 4;
  // align to 256B for frag buffers
  p = (char*)(((size_t)p + 255) & ~(size_t)255);
  ushort* wfr[4]; float* wss[4]; float* wsd[4];
  for (int i = 0; i < 4; ++i) {
    wfr[i] = (ushort*)p;  p += 128 * 128 * 2;     // 32 KB each
  }
  for (int i = 0; i < 4; ++i) {
    wss[i] = (float*)p;   p += 128 * 4;
    wsd[i] = (float*)p;   p += 128 * 4;
  }

  // ---- W prep (tiny, once per call) ----
  const float* Wl[4]  = {Wx1, Wx2, Wy1, Wy2};
  const float* asl[4] = {asx1, asx2, asy1, asy2};
  const float* adl[4] = {adx1, adx2, ady1, ady2};
  for (int i = 0; i < 4; ++i) {
    wprep_k<<<dim3(64), 256, 0, stream>>>(Wl[i], wfr[i], 128);
    wsprep_k<<<dim3(1), 128, 0, stream>>>(Wl[i], asl[i], adl[i], wss[i], wsd[i], 128);
  }

  build_csr(srcx, dstx, E, N, offx, srcxs, cur, bsum, stream);
  build_csr(srcy, dsty, E, N, offy, srcys, cur, bsum, stream);

  // x branch
  run_gat_layer(x,     0, wfr[0], wss[0], wsd[0], bx1, offx, srcxs, N, hbf, es, ed, inter, stream);
  run_gat_layer(inter, 1, wfr[1], wss[1], wsd[1], bx2, offx, srcxs, N, hbf, es, ed, hx,    stream);
  // y branch
  run_gat_layer(x,     0, wfr[2], wss[2], wsd[2], by1, offy, srcys, N, hbf, es, ed, inter, stream);
  run_gat_layer(inter, 1, wfr[3], wss[3], wsd[3], by2, offy, srcys, N, hbf, es, ed, hy,    stream);

  // head: only the 10000 indexed rows
  float* fcbuf = (float*)hbf;     // 10000 x 256 fp32 (reuse)
  float* fcout = inter;           // 10000 x 128 fp32 (reuse)
  gather_k<<<dim3((Midx * 256 + 255) / 256), 256, 0, stream>>>(idx, hx, hy, fcbuf, Midx);
  gemm_k<<<dim3((Midx + 63) / 64), 256, 0, stream>>>(fcbuf, Wfc, bfc, fcout, Midx, 256, 0);
  head_k<<<dim3((Midx + 3) / 4), 256, 0, stream>>>(fcout, Wout, bout, (float*)d_out, Midx);
}

// Round 8
// 389.540 us; speedup vs baseline: 1.4451x; 1.1267x over previous
//
#include <hip/hip_runtime.h>

// ---------------------------------------------------------------------------
// GAT (heads=1) x2 layers x2 branches + FC head.
// R8: bf16 node features end-to-end.
//  - aggr computes NEXT layer's es/ed exactly in fp32 from its register
//    values (es2 = relu(out).(W2@a2)), then writes out as bf16.
//  - layer-2 / FC GEMMs use mgemm_b_k: bf16 A rows load directly as MFMA
//    A-fragments (no conversion, half fetch). Layer-1 keeps fp32-A mgemm
//    with fused exact es/ed (es = A.(W@a)).
//  - FC head on MFMA (fixes 157-block grid-starved fp32 GEMM @44us).
//  - aggr gather uses readlane (wave-uniform index) instead of shfl.
// Softmax without max pass (shift-invariant; self-loops guarantee nonempty
// segments; |logits| small). fp32: x, es/ed, softmax, biases, Wout head.
// ---------------------------------------------------------------------------

typedef __attribute__((ext_vector_type(8))) short bf16x8;
typedef __attribute__((ext_vector_type(4))) float f32x4;

__device__ __forceinline__ unsigned bf16rne(float x) {
  unsigned u = __float_as_uint(x);
  return (u + 0x7fffu + ((u >> 16) & 1u)) >> 16;
}
__device__ __forceinline__ unsigned pack2(float lo, float hi) {
  return bf16rne(lo) | (bf16rne(hi) << 16);
}
__device__ __forceinline__ float bflo(unsigned u) { return __uint_as_float(u << 16); }
__device__ __forceinline__ float bfhi(unsigned u) { return __uint_as_float(u & 0xffff0000u); }

// ---------------- W prep: fragment packing + ws = W @ a ----------------------
// B-frag for v_mfma_f32_16x16x32_bf16: lane l supplies
// B[k = kt*32 + (l>>4)*8 + i][col = ct*16 + (l&15)], i=0..7.
// wfrag element index = ((kt*8 + ct)*64 + lane)*8 + i.   (validated R7)
__global__ __launch_bounds__(256) void wprep_k(
    const float* __restrict__ W, ushort* __restrict__ wfrag, int K)
{
  int e = blockIdx.x * 256 + threadIdx.x;
  if (e >= K * 128) return;
  int i    = e & 7;
  int lane = (e >> 3) & 63;
  int ct   = (e >> 9) & 7;
  int kt   = e >> 12;
  int k    = kt * 32 + ((lane >> 4) << 3) + i;
  int col  = ct * 16 + (lane & 15);
  wfrag[e] = (ushort)bf16rne(W[(size_t)k * 128 + col]);
}

__global__ __launch_bounds__(128) void wsprep_k(
    const float* __restrict__ W, const float* __restrict__ a_s,
    const float* __restrict__ a_d, float* __restrict__ ws_s,
    float* __restrict__ ws_d, int K)
{
  int k = blockIdx.x * 128 + threadIdx.x;
  if (k >= K) return;
  float s = 0.f, d = 0.f;
  for (int c = 0; c < 128; ++c) {
    float w = W[(size_t)k * 128 + c];
    s += w * a_s[c];
    d += w * a_d[c];
  }
  ws_s[k] = s; ws_d[k] = d;
}

// ---------------- MFMA GEMM, fp32 A (layer 1): h(bf16), es/ed fp32 exact -----
__global__ __launch_bounds__(256) void mgemm_k(
    const float* __restrict__ A, const ushort* __restrict__ wfrag,
    const float* __restrict__ ws_s, const float* __restrict__ ws_d,
    ushort* __restrict__ Cb, float* __restrict__ es, float* __restrict__ ed,
    int M, int K, int relu_in)
{
  const int tid = threadIdx.x;
  const int w   = tid >> 6;
  const int l   = tid & 63;
  const int rowbase = blockIdx.x * 64 + w * 16;
  const int arow    = rowbase + (l & 15);
  const bool valid  = arow < M;
  const int kofs    = (l >> 4) * 8;
  const float* Ap   = A + (size_t)arow * K + kofs;

  f32x4 acc[8];
#pragma unroll
  for (int ct = 0; ct < 8; ++ct) acc[ct] = (f32x4){0.f, 0.f, 0.f, 0.f};
  float esp = 0.f, edp = 0.f;

  const int T = K >> 5;
  for (int kt = 0; kt < T; ++kt) {
    float4 a0 = make_float4(0.f, 0.f, 0.f, 0.f), a1 = a0;
    if (valid) {
      a0 = *reinterpret_cast<const float4*>(Ap + kt * 32);
      a1 = *reinterpret_cast<const float4*>(Ap + kt * 32 + 4);
    }
    if (relu_in) {
      a0.x = fmaxf(a0.x, 0.f); a0.y = fmaxf(a0.y, 0.f);
      a0.z = fmaxf(a0.z, 0.f); a0.w = fmaxf(a0.w, 0.f);
      a1.x = fmaxf(a1.x, 0.f); a1.y = fmaxf(a1.y, 0.f);
      a1.z = fmaxf(a1.z, 0.f); a1.w = fmaxf(a1.w, 0.f);
    }
    {
      float4 s0 = *reinterpret_cast<const float4*>(ws_s + kt * 32 + kofs);
      float4 s1 = *reinterpret_cast<const float4*>(ws_s + kt * 32 + kofs + 4);
      float4 d0 = *reinterpret_cast<const float4*>(ws_d + kt * 32 + kofs);
      float4 d1 = *reinterpret_cast<const float4*>(ws_d + kt * 32 + kofs + 4);
      esp += a0.x*s0.x + a0.y*s0.y + a0.z*s0.z + a0.w*s0.w
           + a1.x*s1.x + a1.y*s1.y + a1.z*s1.z + a1.w*s1.w;
      edp += a0.x*d0.x + a0.y*d0.y + a0.z*d0.z + a0.w*d0.w
           + a1.x*d1.x + a1.y*d1.y + a1.z*d1.z + a1.w*d1.w;
    }
    bf16x8 af;
    af[0] = (short)bf16rne(a0.x); af[1] = (short)bf16rne(a0.y);
    af[2] = (short)bf16rne(a0.z); af[3] = (short)bf16rne(a0.w);
    af[4] = (short)bf16rne(a1.x); af[5] = (short)bf16rne(a1.y);
    af[6] = (short)bf16rne(a1.z); af[7] = (short)bf16rne(a1.w);
#pragma unroll
    for (int ct = 0; ct < 8; ++ct) {
      bf16x8 bf = *reinterpret_cast<const bf16x8*>(
          wfrag + (((size_t)(kt * 8 + ct) * 64 + l) << 3));
      acc[ct] = __builtin_amdgcn_mfma_f32_16x16x32_bf16(af, bf, acc[ct], 0, 0, 0);
    }
  }

  const int ccol  = l & 15;
  const int crow0 = rowbase + (l >> 4) * 4;
#pragma unroll
  for (int r = 0; r < 4; ++r) {
    int row = crow0 + r;
    if (row < M) {
#pragma unroll
      for (int ct = 0; ct < 8; ++ct)
        Cb[(size_t)row * 128 + ct * 16 + ccol] = (ushort)bf16rne(acc[ct][r]);
    }
  }

  esp += __shfl_xor(esp, 16, 64); esp += __shfl_xor(esp, 32, 64);
  edp += __shfl_xor(edp, 16, 64); edp += __shfl_xor(edp, 32, 64);
  if (l < 16 && valid) { es[arow] = esp; ed[arow] = edp; }
}

// ---------------- MFMA GEMM, bf16 A (layer 2 + FC): h(bf16) ------------------
__global__ __launch_bounds__(256) void mgemm_b_k(
    const ushort* __restrict__ A, const ushort* __restrict__ wfrag,
    ushort* __restrict__ Cb, int M, int K, int relu_in)
{
  const int tid = threadIdx.x;
  const int w   = tid >> 6;
  const int l   = tid & 63;
  const int rowbase = blockIdx.x * 64 + w * 16;
  const int arow    = rowbase + (l & 15);
  const bool valid  = arow < M;
  const int kofs    = (l >> 4) * 8;
  const ushort* Ap  = A + (size_t)arow * K + kofs;

  f32x4 acc[8];
#pragma unroll
  for (int ct = 0; ct < 8; ++ct) acc[ct] = (f32x4){0.f, 0.f, 0.f, 0.f};

  const int T = K >> 5;
  for (int kt = 0; kt < T; ++kt) {
    bf16x8 af = (bf16x8){0, 0, 0, 0, 0, 0, 0, 0};
    if (valid) af = *reinterpret_cast<const bf16x8*>(Ap + kt * 32);
    if (relu_in) {
#pragma unroll
      for (int i = 0; i < 8; ++i) {
        unsigned v = (unsigned short)af[i];
        af[i] = (short)((v & 0x8000u) ? 0u : v);
      }
    }
#pragma unroll
    for (int ct = 0; ct < 8; ++ct) {
      bf16x8 bf = *reinterpret_cast<const bf16x8*>(
          wfrag + (((size_t)(kt * 8 + ct) * 64 + l) << 3));
      acc[ct] = __builtin_amdgcn_mfma_f32_16x16x32_bf16(af, bf, acc[ct], 0, 0, 0);
    }
  }

  const int ccol  = l & 15;
  const int crow0 = rowbase + (l >> 4) * 4;
#pragma unroll
  for (int r = 0; r < 4; ++r) {
    int row = crow0 + r;
    if (row < M) {
#pragma unroll
      for (int ct = 0; ct < 8; ++ct)
        Cb[(size_t)row * 128 + ct * 16 + ccol] = (ushort)bf16rne(acc[ct][r]);
    }
  }
}

// ---------------- CSR build (by dst, self-loop at slot off[i]) ----------------

__global__ __launch_bounds__(256) void deg_init_k(int* __restrict__ deg, int* __restrict__ off, int N, int total)
{
  int i = blockIdx.x * 256 + threadIdx.x;
  if (i < N) deg[i] = 1;
  if (i == 0) off[N] = total;
}

__global__ __launch_bounds__(256) void deg_k(const int* __restrict__ dst, int* __restrict__ deg, int E)
{
  int e = blockIdx.x * 256 + threadIdx.x;
  if (e < E) atomicAdd(&deg[dst[e]], 1);
}

__global__ __launch_bounds__(256) void scan1_k(
    const int* __restrict__ deg, int* __restrict__ off, int* __restrict__ bsum, int N)
{
  __shared__ int ts[256];
  int base = blockIdx.x * 1024 + threadIdx.x * 4;
  int v[4]; int s = 0;
#pragma unroll
  for (int t = 0; t < 4; ++t) { v[t] = (base + t < N) ? deg[base + t] : 0; s += v[t]; }
  ts[threadIdx.x] = s;
  __syncthreads();
  int mine = s;
#pragma unroll
  for (int o = 1; o < 256; o <<= 1) {
    int x = (threadIdx.x >= o) ? ts[threadIdx.x - o] : 0;
    __syncthreads();
    ts[threadIdx.x] += x;
    __syncthreads();
  }
  int run = ts[threadIdx.x] - mine;
#pragma unroll
  for (int t = 0; t < 4; ++t) {
    if (base + t < N) off[base + t] = run;
    run += v[t];
  }
  if (threadIdx.x == 255) bsum[blockIdx.x] = ts[255];
}

__global__ __launch_bounds__(256) void scan2_k(int* __restrict__ bsum, int nb)
{
  __shared__ int ts[256];
  int v = (threadIdx.x < nb) ? bsum[threadIdx.x] : 0;
  ts[threadIdx.x] = v;
  __syncthreads();
  int mine = v;
#pragma unroll
  for (int o = 1; o < 256; o <<= 1) {
    int x = (threadIdx.x >= o) ? ts[threadIdx.x - o] : 0;
    __syncthreads();
    ts[threadIdx.x] += x;
    __syncthreads();
  }
  if (threadIdx.x < nb) bsum[threadIdx.x] = ts[threadIdx.x] - mine;
}

__global__ __launch_bounds__(256) void scan3_k(int* __restrict__ off, const int* __restrict__ bsum, int N)
{
  int i = blockIdx.x * 256 + threadIdx.x;
  if (i < N) off[i] += bsum[i >> 10];
}

__global__ __launch_bounds__(256) void fill_self_k(
    const int* __restrict__ off, int* __restrict__ srcs, int* __restrict__ cur, int N)
{
  int i = blockIdx.x * 256 + threadIdx.x;
  if (i < N) { srcs[off[i]] = i; cur[i] = 1; }
}

__global__ __launch_bounds__(256) void fill_edge_k(
    const int* __restrict__ src, const int* __restrict__ dst,
    const int* __restrict__ off, int* __restrict__ cur, int* __restrict__ srcs, int E)
{
  int e = blockIdx.x * 256 + threadIdx.x;
  if (e < E) {
    int d = dst[e];
    int j = off[d] + atomicAdd(&cur[d], 1);
    srcs[j] = src[e];
  }
}

// ---------------- fused per-node softmax + aggregate (one wave per node) -----
// h packed bf16 (64 uints/row). Gather index is wave-uniform -> readlane
// (SGPR broadcast). Writes out as bf16 (packed). If ws2_s != null, also
// computes NEXT layer's es/ed exactly in fp32: es2 = relu(out) . ws2.
__global__ __launch_bounds__(256) void gat_aggr_k(
    const int* __restrict__ off, const int* __restrict__ srcs,
    const float* __restrict__ es, const float* __restrict__ ed,
    const unsigned* __restrict__ h, const float* __restrict__ bias,
    unsigned* __restrict__ outb,
    const float* __restrict__ ws2_s, const float* __restrict__ ws2_d,
    float* __restrict__ es2, float* __restrict__ ed2, int N)
{
  int w    = (blockIdx.x * 256 + threadIdx.x) >> 6;
  int lane = threadIdx.x & 63;
  if (w >= N) return;
  int b  = off[w];
  int e2 = off[w + 1];
  float edv = ed[w];
  float ax = 0.f, ay = 0.f, dsum = 0.f;

  for (int c0 = b; c0 < e2; c0 += 64) {
    int nc = e2 - c0; if (nc > 64) nc = 64;
    int  sl = srcs[c0 + (lane < nc ? lane : 0)];
    float pl = 0.f;
    if (lane < nc) {
      float l = es[sl] + edv;
      l = (l > 0.f) ? l : 0.2f * l;
      pl = expf(l);
    }
    dsum += pl;

    for (int e = 0; e < nc; e += 8) {
      unsigned hv[8]; float pp[8];
#pragma unroll
      for (int k = 0; k < 8; ++k) {
        int ok = (e + k) < nc;
        int s  = __builtin_amdgcn_readlane(sl, e + k);   // uniform -> SGPR
        float pk = __int_as_float(__builtin_amdgcn_readlane(__float_as_int(pl), e + k));
        pp[k] = ok ? pk : 0.f;
        hv[k] = h[(size_t)s * 64 + lane];
      }
#pragma unroll
      for (int k = 0; k < 8; ++k) {
        ax += pp[k] * bflo(hv[k]);
        ay += pp[k] * bfhi(hv[k]);
      }
    }
  }

#pragma unroll
  for (int o = 32; o > 0; o >>= 1) dsum += __shfl_xor(dsum, o, 64);
  float inv = 1.f / dsum;
  float o0 = ax * inv + bias[lane * 2];
  float o1 = ay * inv + bias[lane * 2 + 1];
  outb[(size_t)w * 64 + lane] = pack2(o0, o1);

  if (ws2_s) {
    float r0 = fmaxf(o0, 0.f), r1 = fmaxf(o1, 0.f);
    float esv = r0 * ws2_s[lane * 2] + r1 * ws2_s[lane * 2 + 1];
    float edv2 = r0 * ws2_d[lane * 2] + r1 * ws2_d[lane * 2 + 1];
#pragma unroll
    for (int o = 32; o > 0; o >>= 1) {
      esv  += __shfl_xor(esv, o, 64);
      edv2 += __shfl_xor(edv2, o, 64);
    }
    if (lane == 0) { es2[w] = esv; ed2[w] = edv2; }
  }
}

// fcbuf[i] (bf16 packed, 128 words) = relu(concat(hx[idx[i]], hy[idx[i]]))
__global__ __launch_bounds__(256) void gather_k(
    const int* __restrict__ idx, const unsigned* __restrict__ hxu,
    const unsigned* __restrict__ hyu, unsigned* __restrict__ outb, int M)
{
  int t = blockIdx.x * 256 + threadIdx.x;
  if (t >= M * 128) return;
  int i = t >> 7, c = t & 127;
  int r = idx[i];
  unsigned v = (c < 64) ? hxu[(size_t)r * 64 + c] : hyu[(size_t)r * 64 + (c - 64)];
  unsigned lo = v & 0xffffu, hi = v >> 16;
  if (lo & 0x8000u) lo = 0;
  if (hi & 0x8000u) hi = 0;
  outb[t] = lo | (hi << 16);
}

// out[i, 0:64] = relu(fc_bf16[i,:] + bfc) @ Wout[128,64] + bout (wave per row)
__global__ __launch_bounds__(256) void head_k(
    const unsigned* __restrict__ fcu, const float* __restrict__ bfc,
    const float* __restrict__ Wout, const float* __restrict__ bout,
    float* __restrict__ out, int M)
{
  __shared__ float rowbuf[4][128];
  int widx = threadIdx.x >> 6;
  int lane = threadIdx.x & 63;
  int i = blockIdx.x * 4 + widx;
  if (i >= M) return;
  unsigned u = fcu[(size_t)i * 64 + lane];
  rowbuf[widx][lane * 2]     = fmaxf(bflo(u) + bfc[lane * 2], 0.f);
  rowbuf[widx][lane * 2 + 1] = fmaxf(bfhi(u) + bfc[lane * 2 + 1], 0.f);
  float acc = bout[lane];
#pragma unroll 8
  for (int k = 0; k < 128; ++k) acc += rowbuf[widx][k] * Wout[k * 64 + lane];
  out[(size_t)i * 64 + lane] = acc;
}

// ---------------------------------------------------------------------------

static void build_csr(const int* src, const int* dst, int E, int N,
                      int* off, int* srcs, int* cur, int* bsum, hipStream_t stream)
{
  const int nb = (N + 1023) / 1024;
  deg_init_k<<<dim3((N + 255) / 256), 256, 0, stream>>>(cur, off, N, E + N);
  deg_k<<<dim3((E + 255) / 256), 256, 0, stream>>>(dst, cur, E);
  scan1_k<<<dim3(nb), 256, 0, stream>>>(cur, off, bsum, N);
  scan2_k<<<dim3(1), 256, 0, stream>>>(bsum, nb);
  scan3_k<<<dim3((N + 255) / 256), 256, 0, stream>>>(off, bsum, N);
  fill_self_k<<<dim3((N + 255) / 256), 256, 0, stream>>>(off, srcs, cur, N);
  fill_edge_k<<<dim3((E + 255) / 256), 256, 0, stream>>>(src, dst, off, cur, srcs, E);
}

extern "C" void kernel_launch(void* const* d_in, const int* in_sizes, int n_in,
                              void* d_out, int out_size, void* d_ws, size_t ws_size,
                              hipStream_t stream)
{
  const float* x    = (const float*)d_in[0];
  const int*   eix  = (const int*)d_in[1];
  const int*   eiy  = (const int*)d_in[2];
  const int*   idx  = (const int*)d_in[3];
  const float* Wx1  = (const float*)d_in[4];
  const float* asx1 = (const float*)d_in[5];
  const float* adx1 = (const float*)d_in[6];
  const float* bx1  = (const float*)d_in[7];
  const float* Wx2  = (const float*)d_in[8];
  const float* asx2 = (const float*)d_in[9];
  const float* adx2 = (const float*)d_in[10];
  const float* bx2  = (const float*)d_in[11];
  const float* Wy1  = (const float*)d_in[12];
  const float* asy1 = (const float*)d_in[13];
  const float* ady1 = (const float*)d_in[14];
  const float* by1  = (const float*)d_in[15];
  const float* Wy2  = (const float*)d_in[16];
  const float* asy2 = (const float*)d_in[17];
  const float* ady2 = (const float*)d_in[18];
  const float* by2  = (const float*)d_in[19];
  const float* Wfc  = (const float*)d_in[20];
  const float* bfc  = (const float*)d_in[21];
  const float* Wout = (const float*)d_in[22];
  const float* bout = (const float*)d_in[23];

  const int N    = in_sizes[0] / 128;   // 50000
  const int E    = in_sizes[1] / 2;     // 600000
  const int Midx = in_sizes[3];         // 10000

  const int* srcx = eix;
  const int* dstx = eix + E;
  const int* srcy = eiy;
  const int* dsty = eiy + E;

  // workspace layout
  char* p = (char*)d_ws;
  const size_t NBH = (size_t)N * 128 * 2;         // 12.8 MB bf16 node buf
  ushort* hbf   = (ushort*)p;   p += NBH;         // GEMM out (bf16), also fcbuf at head
  ushort* interb= (ushort*)p;   p += NBH;         // layer-1 aggr out (bf16), also fc at head
  ushort* hxb   = (ushort*)p;   p += NBH;
  ushort* hyb   = (ushort*)p;   p += NBH;
  float* es   = (float*)p;      p += (size_t)N * 4;
  float* ed   = (float*)p;      p += (size_t)N * 4;
  float* es2  = (float*)p;      p += (size_t)N * 4;
  float* ed2  = (float*)p;      p += (size_t)N * 4;
  int*   offx = (int*)p;        p += (size_t)(N + 1) * 4;
  int*   offy = (int*)p;        p += (size_t)(N + 1) * 4;
  int*   cur  = (int*)p;        p += (size_t)N * 4;
  int*   bsum = (int*)p;        p += 256 * 4;
  int*   srcxs= (int*)p;        p += (size_t)(E + N) * 4;
  int*   srcys= (int*)p;        p += (size_t)(E + N) * 4;
  p = (char*)(((size_t)p + 255) & ~(size_t)255);
  ushort* wfr[4]; float* wss[4]; float* wsd[4];
  for (int i = 0; i < 4; ++i) { wfr[i] = (ushort*)p; p += 128 * 128 * 2; }
  ushort* wfrfc = (ushort*)p;   p += 256 * 128 * 2;
  for (int i = 0; i < 4; ++i) {
    wss[i] = (float*)p;  p += 128 * 4;
    wsd[i] = (float*)p;  p += 128 * 4;
  }

  // ---- W prep (tiny, once per call) ----
  const float* Wl[4]  = {Wx1, Wx2, Wy1, Wy2};
  const float* asl[4] = {asx1, asx2, asy1, asy2};
  const float* adl[4] = {adx1, adx2, ady1, ady2};
  for (int i = 0; i < 4; ++i) {
    wprep_k<<<dim3(64), 256, 0, stream>>>(Wl[i], wfr[i], 128);
    wsprep_k<<<dim3(1), 128, 0, stream>>>(Wl[i], asl[i], adl[i], wss[i], wsd[i], 128);
  }
  wprep_k<<<dim3(128), 256, 0, stream>>>(Wfc, wfrfc, 256);

  build_csr(srcx, dstx, E, N, offx, srcxs, cur, bsum, stream);
  build_csr(srcy, dsty, E, N, offy, srcys, cur, bsum, stream);

  const int GB = (N + 63) / 64;     // 782
  const int GA = (N + 3) / 4;       // 12500

  // ---- x branch ----
  mgemm_k<<<dim3(GB), 256, 0, stream>>>(x, wfr[0], wss[0], wsd[0], hbf, es, ed, N, 128, 0);
  gat_aggr_k<<<dim3(GA), 256, 0, stream>>>(offx, srcxs, es, ed, (const unsigned*)hbf, bx1,
                                           (unsigned*)interb, wss[1], wsd[1], es2, ed2, N);
  mgemm_b_k<<<dim3(GB), 256, 0, stream>>>(interb, wfr[1], hbf, N, 128, 1);
  gat_aggr_k<<<dim3(GA), 256, 0, stream>>>(offx, srcxs, es2, ed2, (const unsigned*)hbf, bx2,
                                           (unsigned*)hxb, nullptr, nullptr, nullptr, nullptr, N);
  // ---- y branch ----
  mgemm_k<<<dim3(GB), 256, 0, stream>>>(x, wfr[2], wss[2], wsd[2], hbf, es, ed, N, 128, 0);
  gat_aggr_k<<<dim3(GA), 256, 0, stream>>>(offy, srcys, es, ed, (const unsigned*)hbf, by1,
                                           (unsigned*)interb, wss[3], wsd[3], es2, ed2, N);
  mgemm_b_k<<<dim3(GB), 256, 0, stream>>>(interb, wfr[3], hbf, N, 128, 1);
  gat_aggr_k<<<dim3(GA), 256, 0, stream>>>(offy, srcys, es2, ed2, (const unsigned*)hbf, by2,
                                           (unsigned*)hyb, nullptr, nullptr, nullptr, nullptr, N);

  // ---- head: only the 10000 indexed rows ----
  unsigned* fcbuf = (unsigned*)hbf;     // Midx x 128 words (bf16 x2)
  ushort*   fcout = interb;             // Midx x 128 bf16
  gather_k<<<dim3((Midx * 128 + 255) / 256), 256, 0, stream>>>(idx, (const unsigned*)hxb,
                                                               (const unsigned*)hyb, fcbuf, Midx);
  mgemm_b_k<<<dim3((Midx + 63) / 64), 256, 0, stream>>>((const ushort*)fcbuf, wfrfc,
                                                        fcout, Midx, 256, 0);
  head_k<<<dim3((Midx + 3) / 4), 256, 0, stream>>>((const unsigned*)fcout, bfc, Wout, bout,
                                                   (float*)d_out, Midx);
}

// Round 9
// 342.485 us; speedup vs baseline: 1.6437x; 1.1374x over previous
//
#include <hip/hip_runtime.h>

// ---------------------------------------------------------------------------
// GAT (heads=1) x2 layers x2 branches + FC head.  R9: dispatch-graph collapse.
//  - x/y branches merged into single 2D-grid kernels (blockIdx.y = graph).
//  - one prep kernel packs all 5 W fragments + 4 ws=W@a pairs.
//  - CSR: memset deg once, scan computes deg+1 (self-loops), 6 dispatches for
//    BOTH graphs.
//  - FC GEMM gathers idx[] rows directly (gather_k fused away).
//  - aggr: double-buffered 8-deep gather pipeline (readlane broadcast).
// Numerics identical to R8: fp32 x/es/ed/softmax/head-Wout; bf16 node
// features; es/ed exact fp32 via ws=W@a fused dots. Softmax without max pass
// (shift-invariant; self-loops guarantee nonempty segments).
// ---------------------------------------------------------------------------

typedef __attribute__((ext_vector_type(8))) short bf16x8;
typedef __attribute__((ext_vector_type(4))) float f32x4;

__device__ __forceinline__ unsigned bf16rne(float x) {
  unsigned u = __float_as_uint(x);
  return (u + 0x7fffu + ((u >> 16) & 1u)) >> 16;
}
__device__ __forceinline__ unsigned pack2(float lo, float hi) {
  return bf16rne(lo) | (bf16rne(hi) << 16);
}
__device__ __forceinline__ float bflo(unsigned u) { return __uint_as_float(u << 16); }
__device__ __forceinline__ float bfhi(unsigned u) { return __uint_as_float(u & 0xffff0000u); }

// ---------------- prep: all W fragments + ws = W@a, one dispatch -------------
// frag mapping (validated R7/R8): element e of matrix -> i=e&7, lane=(e>>3)&63,
// ct=(e>>9)&7, kt=e>>12; B[k=kt*32+(lane>>4)*8+i][col=ct*16+(lane&15)].
// wfrALL layout: layers 0..3 at m*16384 (K=128), FC at 65536 (K=256).
// wsALL: layer m at m*256: [0:128)=W@a_src, [128:256)=W@a_dst.
__global__ __launch_bounds__(256) void prep_all_k(
    const float* __restrict__ W0, const float* __restrict__ W1,
    const float* __restrict__ W2, const float* __restrict__ W3,
    const float* __restrict__ W4,
    const float* __restrict__ as0, const float* __restrict__ ad0,
    const float* __restrict__ as1, const float* __restrict__ ad1,
    const float* __restrict__ as2, const float* __restrict__ ad2,
    const float* __restrict__ as3, const float* __restrict__ ad3,
    ushort* __restrict__ wfrALL, float* __restrict__ wsALL)
{
  int b = blockIdx.x;
  if (b < 384) {
    int e = b * 256 + threadIdx.x;
    const float* W; int le;
    if (e < 65536) { int m = e >> 14; le = e & 16383;
      W = (m == 0) ? W0 : (m == 1) ? W1 : (m == 2) ? W2 : W3; }
    else { le = e - 65536; W = W4; }
    int i = le & 7, lane = (le >> 3) & 63, ct = (le >> 9) & 7, kt = le >> 12;
    int k   = kt * 32 + ((lane >> 4) << 3) + i;
    int col = ct * 16 + (lane & 15);
    wfrALL[e] = (ushort)bf16rne(W[(size_t)k * 128 + col]);
  } else {
    int layer = (b - 384) * 2 + (threadIdx.x >> 7);
    int k = threadIdx.x & 127;
    const float* W  = (layer == 0) ? W0 : (layer == 1) ? W1 : (layer == 2) ? W2 : W3;
    const float* as_= (layer == 0) ? as0 : (layer == 1) ? as1 : (layer == 2) ? as2 : as3;
    const float* ad_= (layer == 0) ? ad0 : (layer == 1) ? ad1 : (layer == 2) ? ad2 : ad3;
    float s = 0.f, d = 0.f;
    for (int c = 0; c < 128; ++c) {
      float w = W[(size_t)k * 128 + c];
      s += w * as_[c]; d += w * ad_[c];
    }
    wsALL[layer * 256 + k]       = s;
    wsALL[layer * 256 + 128 + k] = d;
  }
}

// ---------------- CSR build, both graphs (blockIdx.y = graph) ----------------
// cur2 (2N ints) zeroed by memset; scan counts deg+1 (self-loop) implicitly.

__global__ __launch_bounds__(256) void deg_k2(
    const int* __restrict__ dstA, const int* __restrict__ dstB,
    int* __restrict__ cur2, int E, int N)
{
  int e = blockIdx.x * 256 + threadIdx.x;
  if (e >= E) return;
  const int* dst = blockIdx.y ? dstB : dstA;
  atomicAdd(&cur2[blockIdx.y * N + dst[e]], 1);
}

__global__ __launch_bounds__(256) void scan1_k2(
    const int* __restrict__ cur2, int* __restrict__ off2,
    int* __restrict__ bsum2, int N)
{
  const int g = blockIdx.y;
  const int* deg = cur2 + (size_t)g * N;
  int* off = off2 + (size_t)g * (N + 1);
  __shared__ int ts[256];
  int base = blockIdx.x * 1024 + threadIdx.x * 4;
  int v[4]; int s = 0;
#pragma unroll
  for (int t = 0; t < 4; ++t) { v[t] = (base + t < N) ? deg[base + t] + 1 : 0; s += v[t]; }
  ts[threadIdx.x] = s;
  __syncthreads();
  int mine = s;
#pragma unroll
  for (int o = 1; o < 256; o <<= 1) {
    int x = (threadIdx.x >= o) ? ts[threadIdx.x - o] : 0;
    __syncthreads();
    ts[threadIdx.x] += x;
    __syncthreads();
  }
  int run = ts[threadIdx.x] - mine;
#pragma unroll
  for (int t = 0; t < 4; ++t) {
    if (base + t < N) off[base + t] = run;
    run += v[t];
  }
  if (threadIdx.x == 255) bsum2[g * 64 + blockIdx.x] = ts[255];
}

__global__ __launch_bounds__(256) void scan2_k2(int* __restrict__ bsum2, int nb)
{
  const int g = blockIdx.x;
  int* bs = bsum2 + g * 64;
  __shared__ int ts[256];
  int v = (threadIdx.x < nb) ? bs[threadIdx.x] : 0;
  ts[threadIdx.x] = v;
  __syncthreads();
  int mine = v;
#pragma unroll
  for (int o = 1; o < 256; o <<= 1) {
    int x = (threadIdx.x >= o) ? ts[threadIdx.x - o] : 0;
    __syncthreads();
    ts[threadIdx.x] += x;
    __syncthreads();
  }
  if (threadIdx.x < nb) bs[threadIdx.x] = ts[threadIdx.x] - mine;
}

__global__ __launch_bounds__(256) void scan3_k2(
    int* __restrict__ off2, const int* __restrict__ bsum2, int N)
{
  const int g = blockIdx.y;
  int i = blockIdx.x * 256 + threadIdx.x;
  if (i < N) off2[(size_t)g * (N + 1) + i] += bsum2[g * 64 + (i >> 10)];
}

__global__ __launch_bounds__(256) void fill_self_k2(
    int* __restrict__ off2, int* __restrict__ srcs2, int* __restrict__ cur2,
    int N, int E)
{
  const int g = blockIdx.y;
  int i = blockIdx.x * 256 + threadIdx.x;
  int* off = off2 + (size_t)g * (N + 1);
  if (i < N) {
    srcs2[(size_t)g * (E + N) + off[i]] = i;
    cur2[(size_t)g * N + i] = 1;
  }
  if (i == 0) off[N] = E + N;
}

__global__ __launch_bounds__(256) void fill_edge_k2(
    const int* __restrict__ srcA, const int* __restrict__ dstA,
    const int* __restrict__ srcB, const int* __restrict__ dstB,
    const int* __restrict__ off2, int* __restrict__ cur2,
    int* __restrict__ srcs2, int E, int N)
{
  const int g = blockIdx.y;
  int e = blockIdx.x * 256 + threadIdx.x;
  if (e >= E) return;
  const int* src = g ? srcB : srcA;
  const int* dst = g ? dstB : dstA;
  int d = dst[e];
  int j = off2[(size_t)g * (N + 1) + d] + atomicAdd(&cur2[(size_t)g * N + d], 1);
  srcs2[(size_t)g * (E + N) + j] = src[e];
}

// ---------------- layer-1 MFMA GEMM (fp32 A = x, shared), both branches ------
__global__ __launch_bounds__(256) void mgemm1_k(
    const float* __restrict__ A, const ushort* __restrict__ wfrALL,
    const float* __restrict__ wsALL, ushort* __restrict__ Cb2,
    float* __restrict__ esA, float* __restrict__ edA, int M)
{
  const int g = blockIdx.y;
  const int m = g ? 2 : 0;
  const ushort* wfrag = wfrALL + (size_t)m * 16384;
  const float* ws_s = wsALL + m * 256;
  const float* ws_d = ws_s + 128;
  ushort* Cb = Cb2 + (size_t)g * M * 128;
  float* es = esA + (size_t)g * M;
  float* ed = edA + (size_t)g * M;

  const int tid = threadIdx.x;
  const int w   = tid >> 6;
  const int l   = tid & 63;
  const int rowbase = blockIdx.x * 64 + w * 16;
  const int arow    = rowbase + (l & 15);
  const bool valid  = arow < M;
  const int kofs    = (l >> 4) * 8;
  const float* Ap   = A + (size_t)arow * 128 + kofs;

  f32x4 acc[8];
#pragma unroll
  for (int ct = 0; ct < 8; ++ct) acc[ct] = (f32x4){0.f, 0.f, 0.f, 0.f};
  float esp = 0.f, edp = 0.f;

  for (int kt = 0; kt < 4; ++kt) {
    float4 a0 = make_float4(0.f, 0.f, 0.f, 0.f), a1 = a0;
    if (valid) {
      a0 = *reinterpret_cast<const float4*>(Ap + kt * 32);
      a1 = *reinterpret_cast<const float4*>(Ap + kt * 32 + 4);
    }
    {
      float4 s0 = *reinterpret_cast<const float4*>(ws_s + kt * 32 + kofs);
      float4 s1 = *reinterpret_cast<const float4*>(ws_s + kt * 32 + kofs + 4);
      float4 d0 = *reinterpret_cast<const float4*>(ws_d + kt * 32 + kofs);
      float4 d1 = *reinterpret_cast<const float4*>(ws_d + kt * 32 + kofs + 4);
      esp += a0.x*s0.x + a0.y*s0.y + a0.z*s0.z + a0.w*s0.w
           + a1.x*s1.x + a1.y*s1.y + a1.z*s1.z + a1.w*s1.w;
      edp += a0.x*d0.x + a0.y*d0.y + a0.z*d0.z + a0.w*d0.w
           + a1.x*d1.x + a1.y*d1.y + a1.z*d1.z + a1.w*d1.w;
    }
    bf16x8 af;
    af[0] = (short)bf16rne(a0.x); af[1] = (short)bf16rne(a0.y);
    af[2] = (short)bf16rne(a0.z); af[3] = (short)bf16rne(a0.w);
    af[4] = (short)bf16rne(a1.x); af[5] = (short)bf16rne(a1.y);
    af[6] = (short)bf16rne(a1.z); af[7] = (short)bf16rne(a1.w);
#pragma unroll
    for (int ct = 0; ct < 8; ++ct) {
      bf16x8 bf = *reinterpret_cast<const bf16x8*>(
          wfrag + (((size_t)(kt * 8 + ct) * 64 + l) << 3));
      acc[ct] = __builtin_amdgcn_mfma_f32_16x16x32_bf16(af, bf, acc[ct], 0, 0, 0);
    }
  }

  const int ccol  = l & 15;
  const int crow0 = rowbase + (l >> 4) * 4;
#pragma unroll
  for (int r = 0; r < 4; ++r) {
    int row = crow0 + r;
    if (row < M) {
#pragma unroll
      for (int ct = 0; ct < 8; ++ct)
        Cb[(size_t)row * 128 + ct * 16 + ccol] = (ushort)bf16rne(acc[ct][r]);
    }
  }

  esp += __shfl_xor(esp, 16, 64); esp += __shfl_xor(esp, 32, 64);
  edp += __shfl_xor(edp, 16, 64); edp += __shfl_xor(edp, 32, 64);
  if (l < 16 && valid) { es[arow] = esp; ed[arow] = edp; }
}

// ---------------- layer-2 MFMA GEMM (bf16 A, relu on load), both branches ----
__global__ __launch_bounds__(256) void mgemm2_k(
    const ushort* __restrict__ A2, const ushort* __restrict__ wfrALL,
    ushort* __restrict__ Cb2, int M)
{
  const int g = blockIdx.y;
  const int m = g ? 3 : 1;
  const ushort* A = A2 + (size_t)g * M * 128;
  const ushort* wfrag = wfrALL + (size_t)m * 16384;
  ushort* Cb = Cb2 + (size_t)g * M * 128;

  const int tid = threadIdx.x;
  const int w   = tid >> 6;
  const int l   = tid & 63;
  const int rowbase = blockIdx.x * 64 + w * 16;
  const int arow    = rowbase + (l & 15);
  const bool valid  = arow < M;
  const int kofs    = (l >> 4) * 8;
  const ushort* Ap  = A + (size_t)arow * 128 + kofs;

  f32x4 acc[8];
#pragma unroll
  for (int ct = 0; ct < 8; ++ct) acc[ct] = (f32x4){0.f, 0.f, 0.f, 0.f};

  for (int kt = 0; kt < 4; ++kt) {
    bf16x8 af = (bf16x8){0, 0, 0, 0, 0, 0, 0, 0};
    if (valid) af = *reinterpret_cast<const bf16x8*>(Ap + kt * 32);
#pragma unroll
    for (int i = 0; i < 8; ++i) {
      unsigned v = (unsigned short)af[i];
      af[i] = (short)((v & 0x8000u) ? 0u : v);     // relu(bf16)
    }
#pragma unroll
    for (int ct = 0; ct < 8; ++ct) {
      bf16x8 bf = *reinterpret_cast<const bf16x8*>(
          wfrag + (((size_t)(kt * 8 + ct) * 64 + l) << 3));
      acc[ct] = __builtin_amdgcn_mfma_f32_16x16x32_bf16(af, bf, acc[ct], 0, 0, 0);
    }
  }

  const int ccol  = l & 15;
  const int crow0 = rowbase + (l >> 4) * 4;
#pragma unroll
  for (int r = 0; r < 4; ++r) {
    int row = crow0 + r;
    if (row < M) {
#pragma unroll
      for (int ct = 0; ct < 8; ++ct)
        Cb[(size_t)row * 128 + ct * 16 + ccol] = (ushort)bf16rne(acc[ct][r]);
    }
  }
}

// ---------------- FC MFMA GEMM with fused idx-gather + relu ------------------
// A row i = relu(concat(hx[idx[i]], hy[idx[i]])), K=256. hxy = [hx ; hy].
__global__ __launch_bounds__(256) void mgemm_fc_k(
    const ushort* __restrict__ hxy, const int* __restrict__ idx,
    const ushort* __restrict__ wfrag, ushort* __restrict__ Cb, int M, int N)
{
  const int tid = threadIdx.x;
  const int w   = tid >> 6;
  const int l   = tid & 63;
  const int rowbase = blockIdx.x * 64 + w * 16;
  const int arow    = rowbase + (l & 15);
  const bool valid  = arow < M;
  const int r       = valid ? idx[arow] : 0;
  const int kofs    = (l >> 4) * 8;

  f32x4 acc[8];
#pragma unroll
  for (int ct = 0; ct < 8; ++ct) acc[ct] = (f32x4){0.f, 0.f, 0.f, 0.f};

  for (int kt = 0; kt < 8; ++kt) {
    const ushort* Ap = (kt < 4)
        ? hxy + (size_t)r * 128 + kt * 32 + kofs
        : hxy + ((size_t)N + r) * 128 + (kt - 4) * 32 + kofs;
    bf16x8 af = (bf16x8){0, 0, 0, 0, 0, 0, 0, 0};
    if (valid) af = *reinterpret_cast<const bf16x8*>(Ap);
#pragma unroll
    for (int i = 0; i < 8; ++i) {
      unsigned v = (unsigned short)af[i];
      af[i] = (short)((v & 0x8000u) ? 0u : v);     // relu(bf16)
    }
#pragma unroll
    for (int ct = 0; ct < 8; ++ct) {
      bf16x8 bf = *reinterpret_cast<const bf16x8*>(
          wfrag + (((size_t)(kt * 8 + ct) * 64 + l) << 3));
      acc[ct] = __builtin_amdgcn_mfma_f32_16x16x32_bf16(af, bf, acc[ct], 0, 0, 0);
    }
  }

  const int ccol  = l & 15;
  const int crow0 = rowbase + (l >> 4) * 4;
#pragma unroll
  for (int rr = 0; rr < 4; ++rr) {
    int row = crow0 + rr;
    if (row < M) {
#pragma unroll
      for (int ct = 0; ct < 8; ++ct)
        Cb[(size_t)row * 128 + ct * 16 + ccol] = (ushort)bf16rne(acc[ct][rr]);
    }
  }
}

// ---------------- fused softmax + aggregate, both graphs ---------------------
// Double-buffered 8-deep gather; readlane broadcast (wave-uniform indices).
// If wsofs >= 0: also next layer's exact fp32 es/ed from register values.
__global__ __launch_bounds__(256) void gat_aggr_k(
    const int* __restrict__ off2, const int* __restrict__ srcs2,
    const float* __restrict__ esIn, const float* __restrict__ edIn,
    const unsigned* __restrict__ h2,
    const float* __restrict__ biasA, const float* __restrict__ biasB,
    unsigned* __restrict__ outb2, const float* __restrict__ wsALL,
    int wsofsA, int wsofsB,
    float* __restrict__ es2, float* __restrict__ ed2, int N, int E)
{
  const int g = blockIdx.y;
  int w    = (blockIdx.x * 256 + threadIdx.x) >> 6;
  int lane = threadIdx.x & 63;
  if (w >= N) return;
  const int* off    = off2 + (size_t)g * (N + 1);
  const int* srcs   = srcs2 + (size_t)g * (E + N);
  const float* es   = esIn + (size_t)g * N;
  const float* ed   = edIn + (size_t)g * N;
  const unsigned* h = h2 + (size_t)g * N * 64;
  const float* bias = g ? biasB : biasA;
  const int wsofs   = g ? wsofsB : wsofsA;

  int b  = off[w];
  int e2 = off[w + 1];
  float edv = ed[w];
  float ax = 0.f, ay = 0.f, dsum = 0.f;

  for (int c0 = b; c0 < e2; c0 += 64) {
    int nc = e2 - c0; if (nc > 64) nc = 64;
    int  sl = srcs[c0 + (lane < nc ? lane : 0)];
    float pl = 0.f;
    if (lane < nc) {
      float l = es[sl] + edv;
      l = (l > 0.f) ? l : 0.2f * l;
      pl = expf(l);
    }
    dsum += pl;

    unsigned hva[8], hvb[8];
    float ppa[8], ppb[8];
#define LOADG(HV, PP, EE)                                                     \
    _Pragma("unroll")                                                         \
    for (int k = 0; k < 8; ++k) {                                             \
      int s = __builtin_amdgcn_readlane(sl, (EE) + k);                        \
      float pk = __int_as_float(                                              \
          __builtin_amdgcn_readlane(__float_as_int(pl), (EE) + k));           \
      PP[k] = ((EE) + k) < nc ? pk : 0.f;                                     \
      HV[k] = h[(size_t)s * 64 + lane];                                       \
    }
#define CONSUME(HV, PP)                                                       \
    _Pragma("unroll")                                                         \
    for (int k = 0; k < 8; ++k) {                                             \
      ax += PP[k] * bflo(HV[k]); ay += PP[k] * bfhi(HV[k]);                   \
    }
    int e0 = 0;
    LOADG(hva, ppa, 0)
    for (;;) {
      int en = e0 + 8;
      if (en < nc) LOADG(hvb, ppb, en)
      CONSUME(hva, ppa)
      e0 = en;
      if (e0 >= nc) break;
      en = e0 + 8;
      if (en < nc) LOADG(hva, ppa, en)
      CONSUME(hvb, ppb)
      e0 = en;
      if (e0 >= nc) break;
    }
#undef LOADG
#undef CONSUME
  }

#pragma unroll
  for (int o = 32; o > 0; o >>= 1) dsum += __shfl_xor(dsum, o, 64);
  float inv = 1.f / dsum;
  float o0 = ax * inv + bias[lane * 2];
  float o1 = ay * inv + bias[lane * 2 + 1];
  outb2[(size_t)g * N * 64 + (size_t)w * 64 + lane] = pack2(o0, o1);

  if (wsofs >= 0) {
    const float* ws_s = wsALL + wsofs;
    const float* ws_d = ws_s + 128;
    float r0 = fmaxf(o0, 0.f), r1 = fmaxf(o1, 0.f);
    float esv = r0 * ws_s[lane * 2] + r1 * ws_s[lane * 2 + 1];
    float edn = r0 * ws_d[lane * 2] + r1 * ws_d[lane * 2 + 1];
#pragma unroll
    for (int o = 32; o > 0; o >>= 1) {
      esv += __shfl_xor(esv, o, 64);
      edn += __shfl_xor(edn, o, 64);
    }
    if (lane == 0) { es2[(size_t)g * N + w] = esv; ed2[(size_t)g * N + w] = edn; }
  }
}

// out[i, 0:64] = relu(fc_bf16[i,:] + bfc) @ Wout[128,64] + bout (wave per row)
__global__ __launch_bounds__(256) void head_k(
    const unsigned* __restrict__ fcu, const float* __restrict__ bfc,
    const float* __restrict__ Wout, const float* __restrict__ bout,
    float* __restrict__ out, int M)
{
  __shared__ float rowbuf[4][128];
  int widx = threadIdx.x >> 6;
  int lane = threadIdx.x & 63;
  int i = blockIdx.x * 4 + widx;
  if (i >= M) return;
  unsigned u = fcu[(size_t)i * 64 + lane];
  rowbuf[widx][lane * 2]     = fmaxf(bflo(u) + bfc[lane * 2], 0.f);
  rowbuf[widx][lane * 2 + 1] = fmaxf(bfhi(u) + bfc[lane * 2 + 1], 0.f);
  float acc = bout[lane];
#pragma unroll 8
  for (int k = 0; k < 128; ++k) acc += rowbuf[widx][k] * Wout[k * 64 + lane];
  out[(size_t)i * 64 + lane] = acc;
}

// ---------------------------------------------------------------------------

extern "C" void kernel_launch(void* const* d_in, const int* in_sizes, int n_in,
                              void* d_out, int out_size, void* d_ws, size_t ws_size,
                              hipStream_t stream)
{
  const float* x    = (const float*)d_in[0];
  const int*   eix  = (const int*)d_in[1];
  const int*   eiy  = (const int*)d_in[2];
  const int*   idx  = (const int*)d_in[3];
  const float* Wx1  = (const float*)d_in[4];
  const float* asx1 = (const float*)d_in[5];
  const float* adx1 = (const float*)d_in[6];
  const float* bx1  = (const float*)d_in[7];
  const float* Wx2  = (const float*)d_in[8];
  const float* asx2 = (const float*)d_in[9];
  const float* adx2 = (const float*)d_in[10];
  const float* bx2  = (const float*)d_in[11];
  const float* Wy1  = (const float*)d_in[12];
  const float* asy1 = (const float*)d_in[13];
  const float* ady1 = (const float*)d_in[14];
  const float* by1  = (const float*)d_in[15];
  const float* Wy2  = (const float*)d_in[16];
  const float* asy2 = (const float*)d_in[17];
  const float* ady2 = (const float*)d_in[18];
  const float* by2  = (const float*)d_in[19];
  const float* Wfc  = (const float*)d_in[20];
  const float* bfc  = (const float*)d_in[21];
  const float* Wout = (const float*)d_in[22];
  const float* bout = (const float*)d_in[23];

  const int N    = in_sizes[0] / 128;   // 50000
  const int E    = in_sizes[1] / 2;     // 600000
  const int Midx = in_sizes[3];         // 10000

  const int* srcx = eix;
  const int* dstx = eix + E;
  const int* srcy = eiy;
  const int* dsty = eiy + E;

  // workspace layout
  char* p = (char*)d_ws;
  const size_t NH = (size_t)N * 128;              // ushorts per node buf per graph
  ushort* hbf2   = (ushort*)p;  p += 2 * NH * 2;  // GEMM outputs (bf16), both graphs
  ushort* inter2 = (ushort*)p;  p += 2 * NH * 2;  // aggr L1 outputs; also FC out
  ushort* hxy    = (ushort*)p;  p += 2 * NH * 2;  // aggr L2 outputs [hx ; hy]
  float* esA  = (float*)p;      p += (size_t)2 * N * 4;
  float* edA  = (float*)p;      p += (size_t)2 * N * 4;
  float* es2A = (float*)p;      p += (size_t)2 * N * 4;
  float* ed2A = (float*)p;      p += (size_t)2 * N * 4;
  int*   off2 = (int*)p;        p += (size_t)2 * (N + 1) * 4;
  int*   cur2 = (int*)p;        p += (size_t)2 * N * 4;
  int*   bsum2= (int*)p;        p += 128 * 4;
  int*   srcs2= (int*)p;        p += (size_t)2 * (E + N) * 4;
  p = (char*)(((size_t)p + 255) & ~(size_t)255);
  ushort* wfrALL = (ushort*)p;  p += 98304 * 2;   // 4x16384 + 32768
  float*  wsALL  = (float*)p;   p += 1024 * 4;

  const int nb = (N + 1023) / 1024;               // 49 (<= 64)
  const dim3 gE((E + 255) / 256, 2);
  const dim3 gN((N + 255) / 256, 2);
  const dim3 gScan(nb, 2);
  const dim3 gGemm((N + 63) / 64, 2);
  const dim3 gAggr((N + 3) / 4, 2);

  // 1. all W prep
  prep_all_k<<<dim3(386), 256, 0, stream>>>(Wx1, Wx2, Wy1, Wy2, Wfc,
                                            asx1, adx1, asx2, adx2,
                                            asy1, ady1, asy2, ady2,
                                            wfrALL, wsALL);
  // 2-8. CSR for both graphs
  hipMemsetAsync(cur2, 0, (size_t)2 * N * 4, stream);
  deg_k2<<<gE, 256, 0, stream>>>(dstx, dsty, cur2, E, N);
  scan1_k2<<<gScan, 256, 0, stream>>>(cur2, off2, bsum2, N);
  scan2_k2<<<dim3(2), 256, 0, stream>>>(bsum2, nb);
  scan3_k2<<<gN, 256, 0, stream>>>(off2, bsum2, N);
  fill_self_k2<<<gN, 256, 0, stream>>>(off2, srcs2, cur2, N, E);
  fill_edge_k2<<<gE, 256, 0, stream>>>(srcx, dstx, srcy, dsty, off2, cur2, srcs2, E, N);

  // 9-12. two GAT layers, both branches per dispatch
  mgemm1_k<<<gGemm, 256, 0, stream>>>(x, wfrALL, wsALL, hbf2, esA, edA, N);
  gat_aggr_k<<<gAggr, 256, 0, stream>>>(off2, srcs2, esA, edA, (const unsigned*)hbf2,
                                        bx1, by1, (unsigned*)inter2, wsALL,
                                        1 * 256, 3 * 256, es2A, ed2A, N, E);
  mgemm2_k<<<gGemm, 256, 0, stream>>>(inter2, wfrALL, hbf2, N);
  gat_aggr_k<<<gAggr, 256, 0, stream>>>(off2, srcs2, es2A, ed2A, (const unsigned*)hbf2,
                                        bx2, by2, (unsigned*)hxy, wsALL,
                                        -1, -1, nullptr, nullptr, N, E);

  // 13-14. head (gather fused into FC GEMM)
  ushort* fcout = inter2;   // Midx x 128 bf16 (inter2 free by now)
  mgemm_fc_k<<<dim3((Midx + 63) / 64), 256, 0, stream>>>(hxy, idx, wfrALL + 65536,
                                                         fcout, Midx, N);
  head_k<<<dim3((Midx + 3) / 4), 256, 0, stream>>>((const unsigned*)fcout, bfc, Wout, bout,
                                                   (float*)d_out, Midx);
}

// Round 10
// 315.945 us; speedup vs baseline: 1.7818x; 1.0840x over previous
//
#include <hip/hip_runtime.h>

// ---------------------------------------------------------------------------
// GAT (heads=1) x2 layers x2 branches + FC head.  R10:
//  - aggr inner loop reverted to R8's straight 8-burst (R9's hand double-
//    buffer regressed 2x: branchy structure defeated compiler scheduling).
//    Bounds select dropped: pad lanes carry p=0, contribute nothing.
//  - scan3 fused into fill_self; cur2 zeroing folded into prep_all_k.
//  - 12 dispatches total. Numerics identical to R8/R9 (absmax 2e-3).
// fp32: x, es/ed (exact via ws=W@a fused dots), softmax, head Wout.
// bf16: node features. Softmax without max pass (shift-invariant; self-loops
// guarantee nonempty segments; |logits| small).
// ---------------------------------------------------------------------------

typedef __attribute__((ext_vector_type(8))) short bf16x8;
typedef __attribute__((ext_vector_type(4))) float f32x4;

__device__ __forceinline__ unsigned bf16rne(float x) {
  unsigned u = __float_as_uint(x);
  return (u + 0x7fffu + ((u >> 16) & 1u)) >> 16;
}
__device__ __forceinline__ unsigned pack2(float lo, float hi) {
  return bf16rne(lo) | (bf16rne(hi) << 16);
}
__device__ __forceinline__ float bflo(unsigned u) { return __uint_as_float(u << 16); }
__device__ __forceinline__ float bfhi(unsigned u) { return __uint_as_float(u & 0xffff0000u); }

// ---------------- prep: W fragments + ws = W@a + cur2 zeroing ----------------
// frag mapping (validated R7-R9): element e -> i=e&7, lane=(e>>3)&63,
// ct=(e>>9)&7, kt=e>>12; B[k=kt*32+(lane>>4)*8+i][col=ct*16+(lane&15)].
// wfrALL: layers 0..3 at m*16384 (K=128), FC at 65536 (K=256).
// wsALL: layer m at m*256: [0:128)=W@a_src, [128:256)=W@a_dst.
__global__ __launch_bounds__(256) void prep_all_k(
    const float* __restrict__ W0, const float* __restrict__ W1,
    const float* __restrict__ W2, const float* __restrict__ W3,
    const float* __restrict__ W4,
    const float* __restrict__ as0, const float* __restrict__ ad0,
    const float* __restrict__ as1, const float* __restrict__ ad1,
    const float* __restrict__ as2, const float* __restrict__ ad2,
    const float* __restrict__ as3, const float* __restrict__ ad3,
    ushort* __restrict__ wfrALL, float* __restrict__ wsALL,
    int* __restrict__ cur2, int N)
{
  int b = blockIdx.x;
  if (b < 384) {
    int e = b * 256 + threadIdx.x;
    const float* W; int le;
    if (e < 65536) { int m = e >> 14; le = e & 16383;
      W = (m == 0) ? W0 : (m == 1) ? W1 : (m == 2) ? W2 : W3; }
    else { le = e - 65536; W = W4; }
    int i = le & 7, lane = (le >> 3) & 63, ct = (le >> 9) & 7, kt = le >> 12;
    int k   = kt * 32 + ((lane >> 4) << 3) + i;
    int col = ct * 16 + (lane & 15);
    wfrALL[e] = (ushort)bf16rne(W[(size_t)k * 128 + col]);
  } else if (b < 386) {
    int layer = (b - 384) * 2 + (threadIdx.x >> 7);
    int k = threadIdx.x & 127;
    const float* W  = (layer == 0) ? W0 : (layer == 1) ? W1 : (layer == 2) ? W2 : W3;
    const float* as_= (layer == 0) ? as0 : (layer == 1) ? as1 : (layer == 2) ? as2 : as3;
    const float* ad_= (layer == 0) ? ad0 : (layer == 1) ? ad1 : (layer == 2) ? ad2 : ad3;
    float s = 0.f, d = 0.f;
    for (int c = 0; c < 128; ++c) {
      float w = W[(size_t)k * 128 + c];
      s += w * as_[c]; d += w * ad_[c];
    }
    wsALL[layer * 256 + k]       = s;
    wsALL[layer * 256 + 128 + k] = d;
  } else {
    int i = (b - 386) * 256 + threadIdx.x;
    if (i < 2 * N) cur2[i] = 0;
  }
}

// ---------------- CSR build, both graphs (blockIdx.y = graph) ----------------

__global__ __launch_bounds__(256) void deg_k2(
    const int* __restrict__ dstA, const int* __restrict__ dstB,
    int* __restrict__ cur2, int E, int N)
{
  int e = blockIdx.x * 256 + threadIdx.x;
  if (e >= E) return;
  const int* dst = blockIdx.y ? dstB : dstA;
  atomicAdd(&cur2[blockIdx.y * N + dst[e]], 1);
}

__global__ __launch_bounds__(256) void scan1_k2(
    const int* __restrict__ cur2, int* __restrict__ off2,
    int* __restrict__ bsum2, int N)
{
  const int g = blockIdx.y;
  const int* deg = cur2 + (size_t)g * N;
  int* off = off2 + (size_t)g * (N + 1);
  __shared__ int ts[256];
  int base = blockIdx.x * 1024 + threadIdx.x * 4;
  int v[4]; int s = 0;
#pragma unroll
  for (int t = 0; t < 4; ++t) { v[t] = (base + t < N) ? deg[base + t] + 1 : 0; s += v[t]; }
  ts[threadIdx.x] = s;
  __syncthreads();
  int mine = s;
#pragma unroll
  for (int o = 1; o < 256; o <<= 1) {
    int x = (threadIdx.x >= o) ? ts[threadIdx.x - o] : 0;
    __syncthreads();
    ts[threadIdx.x] += x;
    __syncthreads();
  }
  int run = ts[threadIdx.x] - mine;
#pragma unroll
  for (int t = 0; t < 4; ++t) {
    if (base + t < N) off[base + t] = run;
    run += v[t];
  }
  if (threadIdx.x == 255) bsum2[g * 64 + blockIdx.x] = ts[255];
}

__global__ __launch_bounds__(256) void scan2_k2(int* __restrict__ bsum2, int nb)
{
  const int g = blockIdx.x;
  int* bs = bsum2 + g * 64;
  __shared__ int ts[256];
  int v = (threadIdx.x < nb) ? bs[threadIdx.x] : 0;
  ts[threadIdx.x] = v;
  __syncthreads();
  int mine = v;
#pragma unroll
  for (int o = 1; o < 256; o <<= 1) {
    int x = (threadIdx.x >= o) ? ts[threadIdx.x - o] : 0;
    __syncthreads();
    ts[threadIdx.x] += x;
    __syncthreads();
  }
  if (threadIdx.x < nb) bs[threadIdx.x] = ts[threadIdx.x] - mine;
}

// scan3 + fill_self fused: finalize offsets, write self-loop, reset cursor.
__global__ __launch_bounds__(256) void scan3_fill_k2(
    int* __restrict__ off2, const int* __restrict__ bsum2,
    int* __restrict__ srcs2, int* __restrict__ cur2, int N, int E)
{
  const int g = blockIdx.y;
  int i = blockIdx.x * 256 + threadIdx.x;
  int* off = off2 + (size_t)g * (N + 1);
  if (i < N) {
    int o = off[i] + bsum2[g * 64 + (i >> 10)];
    off[i] = o;
    srcs2[(size_t)g * (E + N) + o] = i;     // self-loop at slot 0
    cur2[(size_t)g * N + i] = 1;
  }
  if (i == 0) off[N] = E + N;
}

__global__ __launch_bounds__(256) void fill_edge_k2(
    const int* __restrict__ srcA, const int* __restrict__ dstA,
    const int* __restrict__ srcB, const int* __restrict__ dstB,
    const int* __restrict__ off2, int* __restrict__ cur2,
    int* __restrict__ srcs2, int E, int N)
{
  const int g = blockIdx.y;
  int e = blockIdx.x * 256 + threadIdx.x;
  if (e >= E) return;
  const int* src = g ? srcB : srcA;
  const int* dst = g ? dstB : dstA;
  int d = dst[e];
  int j = off2[(size_t)g * (N + 1) + d] + atomicAdd(&cur2[(size_t)g * N + d], 1);
  srcs2[(size_t)g * (E + N) + j] = src[e];
}

// ---------------- layer-1 MFMA GEMM (fp32 A = x, shared), both branches ------
__global__ __launch_bounds__(256) void mgemm1_k(
    const float* __restrict__ A, const ushort* __restrict__ wfrALL,
    const float* __restrict__ wsALL, ushort* __restrict__ Cb2,
    float* __restrict__ esA, float* __restrict__ edA, int M)
{
  const int g = blockIdx.y;
  const int m = g ? 2 : 0;
  const ushort* wfrag = wfrALL + (size_t)m * 16384;
  const float* ws_s = wsALL + m * 256;
  const float* ws_d = ws_s + 128;
  ushort* Cb = Cb2 + (size_t)g * M * 128;
  float* es = esA + (size_t)g * M;
  float* ed = edA + (size_t)g * M;

  const int tid = threadIdx.x;
  const int w   = tid >> 6;
  const int l   = tid & 63;
  const int rowbase = blockIdx.x * 64 + w * 16;
  const int arow    = rowbase + (l & 15);
  const bool valid  = arow < M;
  const int kofs    = (l >> 4) * 8;
  const float* Ap   = A + (size_t)arow * 128 + kofs;

  f32x4 acc[8];
#pragma unroll
  for (int ct = 0; ct < 8; ++ct) acc[ct] = (f32x4){0.f, 0.f, 0.f, 0.f};
  float esp = 0.f, edp = 0.f;

  for (int kt = 0; kt < 4; ++kt) {
    float4 a0 = make_float4(0.f, 0.f, 0.f, 0.f), a1 = a0;
    if (valid) {
      a0 = *reinterpret_cast<const float4*>(Ap + kt * 32);
      a1 = *reinterpret_cast<const float4*>(Ap + kt * 32 + 4);
    }
    {
      float4 s0 = *reinterpret_cast<const float4*>(ws_s + kt * 32 + kofs);
      float4 s1 = *reinterpret_cast<const float4*>(ws_s + kt * 32 + kofs + 4);
      float4 d0 = *reinterpret_cast<const float4*>(ws_d + kt * 32 + kofs);
      float4 d1 = *reinterpret_cast<const float4*>(ws_d + kt * 32 + kofs + 4);
      esp += a0.x*s0.x + a0.y*s0.y + a0.z*s0.z + a0.w*s0.w
           + a1.x*s1.x + a1.y*s1.y + a1.z*s1.z + a1.w*s1.w;
      edp += a0.x*d0.x + a0.y*d0.y + a0.z*d0.z + a0.w*d0.w
           + a1.x*d1.x + a1.y*d1.y + a1.z*d1.z + a1.w*d1.w;
    }
    bf16x8 af;
    af[0] = (short)bf16rne(a0.x); af[1] = (short)bf16rne(a0.y);
    af[2] = (short)bf16rne(a0.z); af[3] = (short)bf16rne(a0.w);
    af[4] = (short)bf16rne(a1.x); af[5] = (short)bf16rne(a1.y);
    af[6] = (short)bf16rne(a1.z); af[7] = (short)bf16rne(a1.w);
#pragma unroll
    for (int ct = 0; ct < 8; ++ct) {
      bf16x8 bf = *reinterpret_cast<const bf16x8*>(
          wfrag + (((size_t)(kt * 8 + ct) * 64 + l) << 3));
      acc[ct] = __builtin_amdgcn_mfma_f32_16x16x32_bf16(af, bf, acc[ct], 0, 0, 0);
    }
  }

  const int ccol  = l & 15;
  const int crow0 = rowbase + (l >> 4) * 4;
#pragma unroll
  for (int r = 0; r < 4; ++r) {
    int row = crow0 + r;
    if (row < M) {
#pragma unroll
      for (int ct = 0; ct < 8; ++ct)
        Cb[(size_t)row * 128 + ct * 16 + ccol] = (ushort)bf16rne(acc[ct][r]);
    }
  }

  esp += __shfl_xor(esp, 16, 64); esp += __shfl_xor(esp, 32, 64);
  edp += __shfl_xor(edp, 16, 64); edp += __shfl_xor(edp, 32, 64);
  if (l < 16 && valid) { es[arow] = esp; ed[arow] = edp; }
}

// ---------------- layer-2 MFMA GEMM (bf16 A, relu on load), both branches ----
__global__ __launch_bounds__(256) void mgemm2_k(
    const ushort* __restrict__ A2, const ushort* __restrict__ wfrALL,
    ushort* __restrict__ Cb2, int M)
{
  const int g = blockIdx.y;
  const int m = g ? 3 : 1;
  const ushort* A = A2 + (size_t)g * M * 128;
  const ushort* wfrag = wfrALL + (size_t)m * 16384;
  ushort* Cb = Cb2 + (size_t)g * M * 128;

  const int tid = threadIdx.x;
  const int w   = tid >> 6;
  const int l   = tid & 63;
  const int rowbase = blockIdx.x * 64 + w * 16;
  const int arow    = rowbase + (l & 15);
  const bool valid  = arow < M;
  const int kofs    = (l >> 4) * 8;
  const ushort* Ap  = A + (size_t)arow * 128 + kofs;

  f32x4 acc[8];
#pragma unroll
  for (int ct = 0; ct < 8; ++ct) acc[ct] = (f32x4){0.f, 0.f, 0.f, 0.f};

  for (int kt = 0; kt < 4; ++kt) {
    bf16x8 af = (bf16x8){0, 0, 0, 0, 0, 0, 0, 0};
    if (valid) af = *reinterpret_cast<const bf16x8*>(Ap + kt * 32);
#pragma unroll
    for (int i = 0; i < 8; ++i) {
      unsigned v = (unsigned short)af[i];
      af[i] = (short)((v & 0x8000u) ? 0u : v);     // relu(bf16)
    }
#pragma unroll
    for (int ct = 0; ct < 8; ++ct) {
      bf16x8 bf = *reinterpret_cast<const bf16x8*>(
          wfrag + (((size_t)(kt * 8 + ct) * 64 + l) << 3));
      acc[ct] = __builtin_amdgcn_mfma_f32_16x16x32_bf16(af, bf, acc[ct], 0, 0, 0);
    }
  }

  const int ccol  = l & 15;
  const int crow0 = rowbase + (l >> 4) * 4;
#pragma unroll
  for (int r = 0; r < 4; ++r) {
    int row = crow0 + r;
    if (row < M) {
#pragma unroll
      for (int ct = 0; ct < 8; ++ct)
        Cb[(size_t)row * 128 + ct * 16 + ccol] = (ushort)bf16rne(acc[ct][r]);
    }
  }
}

// ---------------- FC MFMA GEMM with fused idx-gather + relu ------------------
__global__ __launch_bounds__(256) void mgemm_fc_k(
    const ushort* __restrict__ hxy, const int* __restrict__ idx,
    const ushort* __restrict__ wfrag, ushort* __restrict__ Cb, int M, int N)
{
  const int tid = threadIdx.x;
  const int w   = tid >> 6;
  const int l   = tid & 63;
  const int rowbase = blockIdx.x * 64 + w * 16;
  const int arow    = rowbase + (l & 15);
  const bool valid  = arow < M;
  const int r       = valid ? idx[arow] : 0;
  const int kofs    = (l >> 4) * 8;

  f32x4 acc[8];
#pragma unroll
  for (int ct = 0; ct < 8; ++ct) acc[ct] = (f32x4){0.f, 0.f, 0.f, 0.f};

  for (int kt = 0; kt < 8; ++kt) {
    const ushort* Ap = (kt < 4)
        ? hxy + (size_t)r * 128 + kt * 32 + kofs
        : hxy + ((size_t)N + r) * 128 + (kt - 4) * 32 + kofs;
    bf16x8 af = (bf16x8){0, 0, 0, 0, 0, 0, 0, 0};
    if (valid) af = *reinterpret_cast<const bf16x8*>(Ap);
#pragma unroll
    for (int i = 0; i < 8; ++i) {
      unsigned v = (unsigned short)af[i];
      af[i] = (short)((v & 0x8000u) ? 0u : v);     // relu(bf16)
    }
#pragma unroll
    for (int ct = 0; ct < 8; ++ct) {
      bf16x8 bf = *reinterpret_cast<const bf16x8*>(
          wfrag + (((size_t)(kt * 8 + ct) * 64 + l) << 3));
      acc[ct] = __builtin_amdgcn_mfma_f32_16x16x32_bf16(af, bf, acc[ct], 0, 0, 0);
    }
  }

  const int ccol  = l & 15;
  const int crow0 = rowbase + (l >> 4) * 4;
#pragma unroll
  for (int rr = 0; rr < 4; ++rr) {
    int row = crow0 + rr;
    if (row < M) {
#pragma unroll
      for (int ct = 0; ct < 8; ++ct)
        Cb[(size_t)row * 128 + ct * 16 + ccol] = (ushort)bf16rne(acc[ct][rr]);
    }
  }
}

// ---------------- fused softmax + aggregate, both graphs ---------------------
// R8-style 8-burst gather, no bounds select: pad lanes carry p=0 so
// out-of-range k's contribute exactly 0 (their sl is a valid row).
__global__ __launch_bounds__(256) void gat_aggr_k(
    const int* __restrict__ off2, const int* __restrict__ srcs2,
    const float* __restrict__ esIn, const float* __restrict__ edIn,
    const unsigned* __restrict__ h2,
    const float* __restrict__ biasA, const float* __restrict__ biasB,
    unsigned* __restrict__ outb2, const float* __restrict__ wsALL,
    int wsofsA, int wsofsB,
    float* __restrict__ es2, float* __restrict__ ed2, int N, int E)
{
  const int g = blockIdx.y;
  int w    = (blockIdx.x * 256 + threadIdx.x) >> 6;
  int lane = threadIdx.x & 63;
  if (w >= N) return;
  const int* off    = off2 + (size_t)g * (N + 1);
  const int* srcs   = srcs2 + (size_t)g * (E + N);
  const float* es   = esIn + (size_t)g * N;
  const float* ed   = edIn + (size_t)g * N;
  const unsigned* h = h2 + (size_t)g * N * 64;
  const float* bias = g ? biasB : biasA;
  const int wsofs   = g ? wsofsB : wsofsA;

  int b  = off[w];
  int e2 = off[w + 1];
  float edv = ed[w];
  float ax = 0.f, ay = 0.f, dsum = 0.f;

  for (int c0 = b; c0 < e2; c0 += 64) {
    int nc = e2 - c0; if (nc > 64) nc = 64;
    int  sl = srcs[c0 + (lane < nc ? lane : 0)];
    float pl = 0.f;
    if (lane < nc) {
      float l = es[sl] + edv;
      l = (l > 0.f) ? l : 0.2f * l;
      pl = expf(l);
    }
    dsum += pl;

    for (int e = 0; e < nc; e += 8) {
      unsigned hv[8]; float pp[8];
#pragma unroll
      for (int k = 0; k < 8; ++k) {
        int s = __builtin_amdgcn_readlane(sl, e + k);
        pp[k] = __int_as_float(__builtin_amdgcn_readlane(__float_as_int(pl), e + k));
        hv[k] = h[(size_t)s * 64 + lane];
      }
#pragma unroll
      for (int k = 0; k < 8; ++k) {
        ax += pp[k] * bflo(hv[k]);
        ay += pp[k] * bfhi(hv[k]);
      }
    }
  }

#pragma unroll
  for (int o = 32; o > 0; o >>= 1) dsum += __shfl_xor(dsum, o, 64);
  float inv = 1.f / dsum;
  float o0 = ax * inv + bias[lane * 2];
  float o1 = ay * inv + bias[lane * 2 + 1];
  outb2[(size_t)g * N * 64 + (size_t)w * 64 + lane] = pack2(o0, o1);

  if (wsofs >= 0) {
    const float* ws_s = wsALL + wsofs;
    const float* ws_d = ws_s + 128;
    float r0 = fmaxf(o0, 0.f), r1 = fmaxf(o1, 0.f);
    float esv = r0 * ws_s[lane * 2] + r1 * ws_s[lane * 2 + 1];
    float edn = r0 * ws_d[lane * 2] + r1 * ws_d[lane * 2 + 1];
#pragma unroll
    for (int o = 32; o > 0; o >>= 1) {
      esv += __shfl_xor(esv, o, 64);
      edn += __shfl_xor(edn, o, 64);
    }
    if (lane == 0) { es2[(size_t)g * N + w] = esv; ed2[(size_t)g * N + w] = edn; }
  }
}

// out[i, 0:64] = relu(fc_bf16[i,:] + bfc) @ Wout[128,64] + bout (wave per row)
__global__ __launch_bounds__(256) void head_k(
    const unsigned* __restrict__ fcu, const float* __restrict__ bfc,
    const float* __restrict__ Wout, const float* __restrict__ bout,
    float* __restrict__ out, int M)
{
  __shared__ float rowbuf[4][128];
  int widx = threadIdx.x >> 6;
  int lane = threadIdx.x & 63;
  int i = blockIdx.x * 4 + widx;
  if (i >= M) return;
  unsigned u = fcu[(size_t)i * 64 + lane];
  rowbuf[widx][lane * 2]     = fmaxf(bflo(u) + bfc[lane * 2], 0.f);
  rowbuf[widx][lane * 2 + 1] = fmaxf(bfhi(u) + bfc[lane * 2 + 1], 0.f);
  float acc = bout[lane];
#pragma unroll 8
  for (int k = 0; k < 128; ++k) acc += rowbuf[widx][k] * Wout[k * 64 + lane];
  out[(size_t)i * 64 + lane] = acc;
}

// ---------------------------------------------------------------------------

extern "C" void kernel_launch(void* const* d_in, const int* in_sizes, int n_in,
                              void* d_out, int out_size, void* d_ws, size_t ws_size,
                              hipStream_t stream)
{
  const float* x    = (const float*)d_in[0];
  const int*   eix  = (const int*)d_in[1];
  const int*   eiy  = (const int*)d_in[2];
  const int*   idx  = (const int*)d_in[3];
  const float* Wx1  = (const float*)d_in[4];
  const float* asx1 = (const float*)d_in[5];
  const float* adx1 = (const float*)d_in[6];
  const float* bx1  = (const float*)d_in[7];
  const float* Wx2  = (const float*)d_in[8];
  const float* asx2 = (const float*)d_in[9];
  const float* adx2 = (const float*)d_in[10];
  const float* bx2  = (const float*)d_in[11];
  const float* Wy1  = (const float*)d_in[12];
  const float* asy1 = (const float*)d_in[13];
  const float* ady1 = (const float*)d_in[14];
  const float* by1  = (const float*)d_in[15];
  const float* Wy2  = (const float*)d_in[16];
  const float* asy2 = (const float*)d_in[17];
  const float* ady2 = (const float*)d_in[18];
  const float* by2  = (const float*)d_in[19];
  const float* Wfc  = (const float*)d_in[20];
  const float* bfc  = (const float*)d_in[21];
  const float* Wout = (const float*)d_in[22];
  const float* bout = (const float*)d_in[23];

  const int N    = in_sizes[0] / 128;   // 50000
  const int E    = in_sizes[1] / 2;     // 600000
  const int Midx = in_sizes[3];         // 10000

  const int* srcx = eix;
  const int* dstx = eix + E;
  const int* srcy = eiy;
  const int* dsty = eiy + E;

  // workspace layout
  char* p = (char*)d_ws;
  const size_t NH = (size_t)N * 128;              // ushorts per node buf per graph
  ushort* hbf2   = (ushort*)p;  p += 2 * NH * 2;  // GEMM outputs (bf16), both graphs
  ushort* inter2 = (ushort*)p;  p += 2 * NH * 2;  // aggr L1 outputs; also FC out
  ushort* hxy    = (ushort*)p;  p += 2 * NH * 2;  // aggr L2 outputs [hx ; hy]
  float* esA  = (float*)p;      p += (size_t)2 * N * 4;
  float* edA  = (float*)p;      p += (size_t)2 * N * 4;
  float* es2A = (float*)p;      p += (size_t)2 * N * 4;
  float* ed2A = (float*)p;      p += (size_t)2 * N * 4;
  int*   off2 = (int*)p;        p += (size_t)2 * (N + 1) * 4;
  int*   cur2 = (int*)p;        p += (size_t)2 * N * 4;
  int*   bsum2= (int*)p;        p += 128 * 4;
  int*   srcs2= (int*)p;        p += (size_t)2 * (E + N) * 4;
  p = (char*)(((size_t)p + 255) & ~(size_t)255);
  ushort* wfrALL = (ushort*)p;  p += 98304 * 2;   // 4x16384 + 32768
  float*  wsALL  = (float*)p;   p += 1024 * 4;

  const int nb = (N + 1023) / 1024;               // 49 (<= 64)
  const int nz = (2 * N + 255) / 256;             // cur2-zero blocks
  const dim3 gE((E + 255) / 256, 2);
  const dim3 gN((N + 255) / 256, 2);
  const dim3 gScan(nb, 2);
  const dim3 gGemm((N + 63) / 64, 2);
  const dim3 gAggr((N + 3) / 4, 2);

  // 1. W prep + cur2 zeroing
  prep_all_k<<<dim3(386 + nz), 256, 0, stream>>>(Wx1, Wx2, Wy1, Wy2, Wfc,
                                                 asx1, adx1, asx2, adx2,
                                                 asy1, ady1, asy2, ady2,
                                                 wfrALL, wsALL, cur2, N);
  // 2-6. CSR for both graphs
  deg_k2<<<gE, 256, 0, stream>>>(dstx, dsty, cur2, E, N);
  scan1_k2<<<gScan, 256, 0, stream>>>(cur2, off2, bsum2, N);
  scan2_k2<<<dim3(2), 256, 0, stream>>>(bsum2, nb);
  scan3_fill_k2<<<gN, 256, 0, stream>>>(off2, bsum2, srcs2, cur2, N, E);
  fill_edge_k2<<<gE, 256, 0, stream>>>(srcx, dstx, srcy, dsty, off2, cur2, srcs2, E, N);

  // 7-10. two GAT layers, both branches per dispatch
  mgemm1_k<<<gGemm, 256, 0, stream>>>(x, wfrALL, wsALL, hbf2, esA, edA, N);
  gat_aggr_k<<<gAggr, 256, 0, stream>>>(off2, srcs2, esA, edA, (const unsigned*)hbf2,
                                        bx1, by1, (unsigned*)inter2, wsALL,
                                        1 * 256, 3 * 256, es2A, ed2A, N, E);
  mgemm2_k<<<gGemm, 256, 0, stream>>>(inter2, wfrALL, hbf2, N);
  gat_aggr_k<<<gAggr, 256, 0, stream>>>(off2, srcs2, es2A, ed2A, (const unsigned*)hbf2,
                                        bx2, by2, (unsigned*)hxy, wsALL,
                                        -1, -1, nullptr, nullptr, N, E);

  // 11-12. head (gather fused into FC GEMM)
  ushort* fcout = inter2;   // Midx x 128 bf16 (inter2 free by now)
  mgemm_fc_k<<<dim3((Midx + 63) / 64), 256, 0, stream>>>(hxy, idx, wfrALL + 65536,
                                                         fcout, Midx, N);
  head_k<<<dim3((Midx + 3) / 4), 256, 0, stream>>>((const unsigned*)fcout, bfc, Wout, bout,
                                                   (float*)d_out, Midx);
}